// Round 1
// baseline (2009.316 us; speedup 1.0000x reference)
//
#include <hip/hip_runtime.h>
#include <hip/hip_bf16.h>
#include <cstdint>
#include <cstddef>

#define BB 8
#define NSPX 1024
#define HH 256
#define WW 256
#define NNODE 8192      // BB*NSPX
#define EE 131072
#define NPIX 524288     // BB*HH*WW
#define CH 256

using bf16 = __hip_bfloat16;

__device__ __forceinline__ float ldf(const float* p) { return *p; }
__device__ __forceinline__ float ldf(const bf16* p)  { return __bfloat162float(*p); }

// ---------------- zero workspace accumulators ----------------
__global__ __launch_bounds__(256) void zero_kernel(int4* p, int n4) {
  int i = blockIdx.x * 256 + threadIdx.x;
  int stride = gridDim.x * 256;
  int4 z = make_int4(0, 0, 0, 0);
  for (; i < n4; i += stride) p[i] = z;
}

// ---------------- seg ids, counts, coord sums ----------------
__global__ __launch_bounds__(256) void seg_cnt_kernel(const int* __restrict__ labels,
                                                      int* __restrict__ segb,
                                                      int* __restrict__ cnt,
                                                      float* __restrict__ sumh,
                                                      float* __restrict__ sumw) {
  int p = blockIdx.x * 256 + threadIdx.x;
  if (p >= NPIX) return;
  int b = p >> 16;
  int h = (p >> 8) & 255;
  int w = p & 255;
  int seg = labels[p] + NSPX * b;
  segb[p] = seg;
  atomicAdd(&cnt[seg], 1);
  atomicAdd(&sumh[seg], (float)h);
  atomicAdd(&sumw[seg], (float)w);
}

// ---------------- edge counting sort by dst ----------------
__global__ __launch_bounds__(256) void edge_cnt_kernel(const int* __restrict__ dst, int* __restrict__ cnt_e) {
  int e = blockIdx.x * 256 + threadIdx.x;
  if (e < EE) atomicAdd(&cnt_e[dst[e]], 1);
}

__global__ __launch_bounds__(1024) void scan_kernel(const int* __restrict__ cnt_e, int* __restrict__ eoff) {
  __shared__ int ps[1024];
  int t = threadIdx.x;
  int base = t * 8;
  int v[8];
  int sum = 0;
#pragma unroll
  for (int i = 0; i < 8; ++i) {
    int x = cnt_e[base + i];
    v[i] = sum;
    sum += x;
  }
  ps[t] = sum;
  __syncthreads();
  for (int off = 1; off < 1024; off <<= 1) {
    int x = (t >= off) ? ps[t - off] : 0;
    __syncthreads();
    ps[t] += x;
    __syncthreads();
  }
  int prev = (t == 0) ? 0 : ps[t - 1];
#pragma unroll
  for (int i = 0; i < 8; ++i) eoff[base + i] = prev + v[i];
  if (t == 1023) eoff[8192] = ps[1023];
}

__global__ __launch_bounds__(256) void edge_scatter_kernel(const int* __restrict__ dst,
                                                           const int* __restrict__ eoff,
                                                           int* __restrict__ ecur,
                                                           int* __restrict__ esorted) {
  int e = blockIdx.x * 256 + threadIdx.x;
  if (e >= EE) return;
  int d = dst[e];
  int pos = eoff[d] + atomicAdd(&ecur[d], 1);
  esorted[pos] = e;
}

// ---------------- channels-last transpose [B,C,P] -> [B,P,C] ----------------
template <typename T>
__global__ __launch_bounds__(256) void transpose_cl(const float* __restrict__ src, T* __restrict__ dst,
                                                    int C, int P) {
  __shared__ float tile[32][33];
  int b = blockIdx.z;
  int p0 = blockIdx.x * 32;
  int c0 = blockIdx.y * 32;
  int tx = threadIdx.x;        // 32
  int ty = threadIdx.y;        // 8
#pragma unroll
  for (int l = 0; l < 4; ++l) {
    int c = c0 + ty + 8 * l;
    tile[ty + 8 * l][tx] = src[((size_t)b * C + c) * P + p0 + tx];
  }
  __syncthreads();
#pragma unroll
  for (int l = 0; l < 4; ++l) {
    int p = p0 + ty + 8 * l;
    dst[((size_t)b * P + p) * C + c0 + tx] = (T)tile[tx][ty + 8 * l];
  }
}

// ---------------- GEMM: out[M][256] = A[M][K] @ W[K][256], fp32 ----------------
__global__ __launch_bounds__(256) void gemm_n256(const float* __restrict__ A, const float* __restrict__ W,
                                                 float* __restrict__ out, int K) {
  const int t = threadIdx.x;
  const int r0 = blockIdx.x * 16;
  const int cw = (t & 63) * 4;
  const int rg = (t >> 6) * 4;
  __shared__ float Xl[16][68];
  float4 acc[4];
#pragma unroll
  for (int i = 0; i < 4; ++i) acc[i] = make_float4(0.f, 0.f, 0.f, 0.f);
  for (int k0 = 0; k0 < K; k0 += 64) {
#pragma unroll
    for (int l = 0; l < 4; ++l) {
      int idx = t + 256 * l;
      int r = idx >> 6, k = idx & 63;
      Xl[r][k] = A[(size_t)(r0 + r) * K + k0 + k];
    }
    __syncthreads();
#pragma unroll
    for (int k4 = 0; k4 < 64; k4 += 4) {
      float4 a[4];
#pragma unroll
      for (int i = 0; i < 4; ++i) a[i] = *(const float4*)&Xl[rg + i][k4];
#pragma unroll
      for (int kk = 0; kk < 4; ++kk) {
        float4 w = *(const float4*)&W[(size_t)(k0 + k4 + kk) * 256 + cw];
#pragma unroll
        for (int i = 0; i < 4; ++i) {
          float av = ((const float*)&a[i])[kk];
          acc[i].x += av * w.x;
          acc[i].y += av * w.y;
          acc[i].z += av * w.z;
          acc[i].w += av * w.w;
        }
      }
    }
    __syncthreads();
  }
#pragma unroll
  for (int i = 0; i < 4; ++i)
    *(float4*)&out[(size_t)(r0 + rg + i) * 256 + cw] = acc[i];
}

// ---------------- per-node 1/count, centroid normalize ----------------
__global__ __launch_bounds__(256) void rcnt_kernel(const int* __restrict__ cnt, float* __restrict__ rcnt,
                                                   float* __restrict__ sumh, float* __restrict__ sumw) {
  int n = blockIdx.x * 256 + threadIdx.x;
  if (n >= NNODE) return;
  int c = cnt[n];
  float r = 1.0f / (float)(c > 1 ? c : 1);
  rcnt[n] = r;
  sumh[n] = sumh[n] * r * (1.0f / 255.0f);  // becomes pc_h
  sumw[n] = sumw[n] * r * (1.0f / 255.0f);  // becomes pc_w
}

// ---------------- bilinear-tap pooling scatter ----------------
template <typename T>
__global__ __launch_bounds__(256) void pool_kernel(const T* __restrict__ Ft, const int* __restrict__ segb,
                                                   float* __restrict__ sum, int hs, float fh) {
  int c = threadIdx.x;
  int p0 = blockIdx.x * 64;
#pragma unroll 1
  for (int pi = 0; pi < 64; ++pi) {
    int p = p0 + pi;
    int seg = segb[p];
    int b = p >> 16;
    int h = (p >> 8) & 255;
    int w = p & 255;
    float ph = h * fh;
    float pw = w * fh;
    int i0 = (int)ph, j0 = (int)pw;
    float th = ph - (float)i0, tw = pw - (float)j0;
    int i1 = min(i0 + 1, hs - 1), j1 = min(j0 + 1, hs - 1);
    const T* base = Ft + (((size_t)b * hs * hs) << 8);
    float f00 = ldf(base + ((((size_t)i0 * hs) + j0) << 8) + c);
    float f01 = ldf(base + ((((size_t)i0 * hs) + j1) << 8) + c);
    float f10 = ldf(base + ((((size_t)i1 * hs) + j0) << 8) + c);
    float f11 = ldf(base + ((((size_t)i1 * hs) + j1) << 8) + c);
    float up = (1.f - th) * ((1.f - tw) * f00 + tw * f01) + th * ((1.f - tw) * f10 + tw * f11);
    atomicAdd(&sum[((size_t)seg << 8) + c], up);
  }
}

// ---------------- edge attr (gaussian of centroid dist) ----------------
__global__ __launch_bounds__(256) void edge_attr_kernel(const int* __restrict__ src, const int* __restrict__ dst,
                                                        const float* __restrict__ pch, const float* __restrict__ pcw,
                                                        float* __restrict__ ew, float* __restrict__ outp) {
  int e = blockIdx.x * 256 + threadIdx.x;
  if (e >= EE) return;
  int s1 = src[e], d1 = dst[e];
  float dh = pch[s1] - pch[d1];
  float dw = pcw[s1] - pcw[d1];
  float ea = expf(-(dh * dh + dw * dw) * 20.0f);
  ew[e] = ea;
  outp[2 * EE + e] = ea;
}

// ---------------- normalize pooled sums -> h0 ----------------
__global__ __launch_bounds__(256) void norm_kernel(const float* __restrict__ sum, const float* __restrict__ rcnt,
                                                   float* __restrict__ out) {
  int i = blockIdx.x * 256 + threadIdx.x;   // over NNODE*CH
  out[i] = sum[i] * rcnt[i >> 8];
}

// ---------------- mix: 0.5*x + 0.5*pool ----------------
__global__ __launch_bounds__(256) void mix_kernel(const float* __restrict__ x, const float* __restrict__ sum,
                                                  const float* __restrict__ rcnt, float* __restrict__ out) {
  int i = blockIdx.x * 256 + threadIdx.x;
  out[i] = 0.5f * x[i] + 0.5f * sum[i] * rcnt[i >> 8];
}

// ---------------- CSR edge aggregation + bias + relu ----------------
__global__ __launch_bounds__(256) void agg_kernel(const float* __restrict__ h, const float* __restrict__ bias,
                                                  const int* __restrict__ eoff, const int* __restrict__ esorted,
                                                  const int* __restrict__ src, const float* __restrict__ ew,
                                                  float* __restrict__ xout) {
  int n = blockIdx.x;
  int c = threadIdx.x;
  int e0 = eoff[n], e1 = eoff[n + 1];
  float acc = 0.f;
  for (int j = e0; j < e1; ++j) {
    int e = esorted[j];
    acc += ew[e] * h[((size_t)src[e] << 8) + c];
  }
  float v = acc + bias[c];
  xout[((size_t)n << 8) + c] = v > 0.f ? v : 0.f;
}

// ---------------- score s = x @ lin_w ----------------
__global__ __launch_bounds__(256) void score_kernel(const float* __restrict__ x, const float* __restrict__ lw,
                                                    float* __restrict__ s) {
  int t = threadIdx.x;
  int n = blockIdx.x * 4 + (t >> 6);
  int lane = t & 63;
  const float* row = x + ((size_t)n << 8);
  float v = row[lane] * lw[lane] + row[lane + 64] * lw[lane + 64] +
            row[lane + 128] * lw[lane + 128] + row[lane + 192] * lw[lane + 192];
#pragma unroll
  for (int off = 32; off > 0; off >>= 1) v += __shfl_down(v, off, 64);
  if (lane == 0) s[n] = v;
}

// ---------------- final sigmoids ----------------
__global__ __launch_bounds__(256) void out_kernel(const float* __restrict__ s, const int* __restrict__ src,
                                                  const int* __restrict__ dst, const int* __restrict__ negs,
                                                  float* __restrict__ outp) {
  int e = blockIdx.x * 256 + threadIdx.x;
  if (e >= EE) return;
  float ss = s[src[e]];
  float a = ss - s[negs[e]];
  float b = ss - s[dst[e]];
  outp[e] = 1.0f / (1.0f + expf(-a));         // dan
  outp[EE + e] = 1.0f / (1.0f + expf(-b));    // dap
}

extern "C" void kernel_launch(void* const* d_in, const int* in_sizes, int n_in,
                              void* d_out, int out_size, void* d_ws, size_t ws_size,
                              hipStream_t stream) {
  const int*   labels = (const int*)d_in[0];
  const float* skip0  = (const float*)d_in[1];
  const float* skip1  = (const float*)d_in[2];
  const float* skip2  = (const float*)d_in[3];
  const int*   edges  = (const int*)d_in[4];
  const int*   negs   = (const int*)d_in[5];
  const float* W0     = (const float*)d_in[6];
  const float* b0     = (const float*)d_in[7];
  const float* W1     = (const float*)d_in[8];
  const float* b1     = (const float*)d_in[9];
  const float* W2     = (const float*)d_in[10];
  const float* b2     = (const float*)d_in[11];
  const float* lw     = (const float*)d_in[12];
  const int* esrc = edges;
  const int* edst = edges + EE;
  float* outp = (float*)d_out;

  // ---- workspace bump allocator (256B aligned) ----
  size_t o = 0;
  char* base = (char*)d_ws;
  auto alloc = [&](size_t bytes) -> void* {
    void* p = base + o;
    o += (bytes + 255) & ~(size_t)255;
    return p;
  };
  // zeroed block (must stay contiguous at front)
  int*   cnt   = (int*)alloc(NNODE * 4);
  float* sumh  = (float*)alloc(NNODE * 4);
  float* sumw  = (float*)alloc(NNODE * 4);
  int*   cnt_e = (int*)alloc(NNODE * 4);
  int*   ecur  = (int*)alloc(NNODE * 4);
  float* sum0  = (float*)alloc((size_t)NNODE * CH * 4);
  float* sum1  = (float*)alloc((size_t)NNODE * CH * 4);
  float* sum2  = (float*)alloc((size_t)NNODE * CH * 4);
  size_t zbytes = o;                  // 25,329,664 bytes, multiple of 16
  // non-zeroed
  float* rcnt    = (float*)alloc(NNODE * 4);
  int*   eoff    = (int*)alloc((NNODE + 1) * 4);
  int*   esorted = (int*)alloc(EE * 4);
  float* ewb     = (float*)alloc(EE * 4);
  int*   segb    = (int*)alloc(NPIX * 4);
  float* bufA    = (float*)alloc((size_t)NNODE * CH * 4);
  float* bufB    = (float*)alloc((size_t)NNODE * CH * 4);
  float* bufC    = (float*)alloc((size_t)NNODE * CH * 4);
  float* F0f     = (float*)bufB;      // [8192][512] overlay on bufB+bufC (16MB), dead before bufB written
  float* F0t     = (float*)alloc((size_t)NNODE * CH * 4);          // pooled-source scale0, fp32
  bf16*  F1t     = (bf16*)alloc((size_t)BB * 4096 * CH * 2);       // 16.7MB
  bf16*  F2t     = (bf16*)alloc((size_t)BB * 16384 * CH * 2);      // 67MB
  float* sbuf    = (float*)alloc(NNODE * 4);
  (void)ws_size; (void)n_in; (void)in_sizes; (void)out_size;

  // 1. zero accumulators
  zero_kernel<<<2048, 256, 0, stream>>>((int4*)d_ws, (int)(zbytes / 16));
  // 2. seg ids + counts + coord sums
  seg_cnt_kernel<<<NPIX / 256, 256, 0, stream>>>(labels, segb, cnt, sumh, sumw);
  // 3-5. edge CSR by dst
  edge_cnt_kernel<<<EE / 256, 256, 0, stream>>>(edst, cnt_e);
  scan_kernel<<<1, 1024, 0, stream>>>(cnt_e, eoff);
  edge_scatter_kernel<<<EE / 256, 256, 0, stream>>>(edst, eoff, ecur, esorted);
  // 6. skip0 -> channels-last fp32 [8192][512]
  transpose_cl<float><<<dim3(1024 / 32, 512 / 32, BB), dim3(32, 8), 0, stream>>>(skip0, F0f, 512, 1024);
  // 7. fold W0: F0t = F0f @ W0   [8192x512]@[512x256]
  gemm_n256<<<NNODE / 16, 256, 0, stream>>>(F0f, W0, F0t, 512);
  // 8-9. skip1/skip2 -> channels-last bf16
  transpose_cl<bf16><<<dim3(4096 / 32, 256 / 32, BB), dim3(32, 8), 0, stream>>>(skip1, F1t, 256, 4096);
  transpose_cl<bf16><<<dim3(16384 / 32, 256 / 32, BB), dim3(32, 8), 0, stream>>>(skip2, F2t, 256, 16384);
  // 10. 1/cnt + centroids
  rcnt_kernel<<<NNODE / 256, 256, 0, stream>>>(cnt, rcnt, sumh, sumw);
  // 11-13. pooling scatter (3 scales)
  pool_kernel<float><<<NPIX / 64, 256, 0, stream>>>(F0t, segb, sum0, 32, 31.0f / 255.0f);
  pool_kernel<bf16><<<NPIX / 64, 256, 0, stream>>>(F1t, segb, sum1, 64, 63.0f / 255.0f);
  pool_kernel<bf16><<<NPIX / 64, 256, 0, stream>>>(F2t, segb, sum2, 128, 127.0f / 255.0f);
  // 14. edge weights + output edge_attr
  edge_attr_kernel<<<EE / 256, 256, 0, stream>>>(esrc, edst, sumh, sumw, ewb, outp);
  // 15. h0 = sum0 / cnt   (== pool(skip0) @ W0)
  norm_kernel<<<(NNODE * CH) / 256, 256, 0, stream>>>(sum0, rcnt, bufA);
  // 16. layer0 aggregate -> x1
  agg_kernel<<<NNODE, 256, 0, stream>>>(bufA, b0, eoff, esorted, esrc, ewb, bufB);
  // 17-19. layer1
  mix_kernel<<<(NNODE * CH) / 256, 256, 0, stream>>>(bufB, sum1, rcnt, bufA);
  gemm_n256<<<NNODE / 16, 256, 0, stream>>>(bufA, W1, bufC, 256);
  agg_kernel<<<NNODE, 256, 0, stream>>>(bufC, b1, eoff, esorted, esrc, ewb, bufB);
  // 20-22. layer2
  mix_kernel<<<(NNODE * CH) / 256, 256, 0, stream>>>(bufB, sum2, rcnt, bufA);
  gemm_n256<<<NNODE / 16, 256, 0, stream>>>(bufA, W2, bufC, 256);
  agg_kernel<<<NNODE, 256, 0, stream>>>(bufC, b2, eoff, esorted, esrc, ewb, bufB);
  // 23. s = x3 @ lin_w
  score_kernel<<<NNODE / 4, 256, 0, stream>>>(bufB, lw, sbuf);
  // 24. dan / dap
  out_kernel<<<EE / 256, 256, 0, stream>>>(sbuf, esrc, edst, negs, outp);
}

// Round 2
// 1026.054 us; speedup vs baseline: 1.9583x; 1.9583x over previous
//
#include <hip/hip_runtime.h>
#include <hip/hip_bf16.h>
#include <cstdint>
#include <cstddef>

#define BB 8
#define NSPX 1024
#define HH 256
#define WW 256
#define NNODE 8192      // BB*NSPX
#define EE 131072
#define NPIX 524288     // BB*HH*WW
#define CH 256

using bf16 = __hip_bfloat16;
typedef unsigned int uint;

// ---------------- zero workspace accumulators ----------------
__global__ __launch_bounds__(256) void zero_kernel(int4* p, int n4) {
  int i = blockIdx.x * 256 + threadIdx.x;
  int stride = gridDim.x * 256;
  int4 z = make_int4(0, 0, 0, 0);
  for (; i < n4; i += stride) p[i] = z;
}

// ---------------- seg ids, counts, coord sums ----------------
__global__ __launch_bounds__(256) void seg_cnt_kernel(const int* __restrict__ labels,
                                                      int* __restrict__ segb,
                                                      int* __restrict__ cnt,
                                                      float* __restrict__ sumh,
                                                      float* __restrict__ sumw) {
  int p = blockIdx.x * 256 + threadIdx.x;
  if (p >= NPIX) return;
  int b = p >> 16;
  int h = (p >> 8) & 255;
  int w = p & 255;
  int seg = labels[p] + NSPX * b;
  segb[p] = seg;
  atomicAdd(&cnt[seg], 1);
  atomicAdd(&sumh[seg], (float)h);
  atomicAdd(&sumw[seg], (float)w);
}

// ---------------- generic 8192-length exclusive scan (1 block) ----------------
__global__ __launch_bounds__(1024) void scan_kernel(const int* __restrict__ cin, int* __restrict__ coff) {
  __shared__ int ps[1024];
  int t = threadIdx.x;
  int base = t * 8;
  int v[8];
  int sum = 0;
#pragma unroll
  for (int i = 0; i < 8; ++i) {
    int x = cin[base + i];
    v[i] = sum;
    sum += x;
  }
  ps[t] = sum;
  __syncthreads();
  for (int off = 1; off < 1024; off <<= 1) {
    int x = (t >= off) ? ps[t - off] : 0;
    __syncthreads();
    ps[t] += x;
    __syncthreads();
  }
  int prev = (t == 0) ? 0 : ps[t - 1];
#pragma unroll
  for (int i = 0; i < 8; ++i) coff[base + i] = prev + v[i];
  if (t == 1023) coff[8192] = ps[1023];
}

// ---------------- edge counting sort by dst ----------------
__global__ __launch_bounds__(256) void edge_cnt_kernel(const int* __restrict__ dst, int* __restrict__ cnt_e) {
  int e = blockIdx.x * 256 + threadIdx.x;
  if (e < EE) atomicAdd(&cnt_e[dst[e]], 1);
}

__global__ __launch_bounds__(256) void edge_scatter_kernel(const int* __restrict__ dst,
                                                           const int* __restrict__ eoff,
                                                           int* __restrict__ ecur,
                                                           int* __restrict__ esorted) {
  int e = blockIdx.x * 256 + threadIdx.x;
  if (e >= EE) return;
  int d = dst[e];
  int pos = eoff[d] + atomicAdd(&ecur[d], 1);
  esorted[pos] = e;
}

// ---------------- pixel counting sort by seg ----------------
__global__ __launch_bounds__(256) void pixel_scatter_kernel(const int* __restrict__ segb,
                                                            const int* __restrict__ poff,
                                                            int* __restrict__ pcur,
                                                            int* __restrict__ psorted) {
  int p = blockIdx.x * 256 + threadIdx.x;
  if (p >= NPIX) return;
  int s = segb[p];
  int pos = poff[s] + atomicAdd(&pcur[s], 1);
  psorted[pos] = p;
}

// ---------------- channels-last transpose [B,C,P] -> [B,P,C] ----------------
template <typename T>
__global__ __launch_bounds__(256) void transpose_cl(const float* __restrict__ src, T* __restrict__ dst,
                                                    int C, int P) {
  __shared__ float tile[32][33];
  int b = blockIdx.z;
  int p0 = blockIdx.x * 32;
  int c0 = blockIdx.y * 32;
  int tx = threadIdx.x;        // 32
  int ty = threadIdx.y;        // 8
#pragma unroll
  for (int l = 0; l < 4; ++l) {
    int c = c0 + ty + 8 * l;
    tile[ty + 8 * l][tx] = src[((size_t)b * C + c) * P + p0 + tx];
  }
  __syncthreads();
#pragma unroll
  for (int l = 0; l < 4; ++l) {
    int p = p0 + ty + 8 * l;
    dst[((size_t)b * P + p) * C + c0 + tx] = (T)tile[tx][ty + 8 * l];
  }
}

// ---------------- GEMM: out[M][256] = A[M][K] @ W[K][256], fp32 ----------------
__global__ __launch_bounds__(256) void gemm_n256(const float* __restrict__ A, const float* __restrict__ W,
                                                 float* __restrict__ out, int K) {
  const int t = threadIdx.x;
  const int r0 = blockIdx.x * 16;
  const int cw = (t & 63) * 4;
  const int rg = (t >> 6) * 4;
  __shared__ float Xl[16][68];
  float4 acc[4];
#pragma unroll
  for (int i = 0; i < 4; ++i) acc[i] = make_float4(0.f, 0.f, 0.f, 0.f);
  for (int k0 = 0; k0 < K; k0 += 64) {
#pragma unroll
    for (int l = 0; l < 4; ++l) {
      int idx = t + 256 * l;
      int r = idx >> 6, k = idx & 63;
      Xl[r][k] = A[(size_t)(r0 + r) * K + k0 + k];
    }
    __syncthreads();
#pragma unroll
    for (int k4 = 0; k4 < 64; k4 += 4) {
      float4 a[4];
#pragma unroll
      for (int i = 0; i < 4; ++i) a[i] = *(const float4*)&Xl[rg + i][k4];
#pragma unroll
      for (int kk = 0; kk < 4; ++kk) {
        float4 w = *(const float4*)&W[(size_t)(k0 + k4 + kk) * 256 + cw];
#pragma unroll
        for (int i = 0; i < 4; ++i) {
          float av = ((const float*)&a[i])[kk];
          acc[i].x += av * w.x;
          acc[i].y += av * w.y;
          acc[i].z += av * w.z;
          acc[i].w += av * w.w;
        }
      }
    }
    __syncthreads();
  }
#pragma unroll
  for (int i = 0; i < 4; ++i)
    *(float4*)&out[(size_t)(r0 + rg + i) * 256 + cw] = acc[i];
}

// ---------------- fp32 -> packed bf16x2 convert ----------------
__global__ __launch_bounds__(256) void cvt_bf16_kernel(const float2* __restrict__ in, uint* __restrict__ out, int n) {
  int i = blockIdx.x * 256 + threadIdx.x;
  if (i >= n) return;
  float2 v = in[i];
  __hip_bfloat162 h = __float22bfloat162_rn(make_float2(v.x, v.y));
  out[i] = *(reinterpret_cast<uint*>(&h));
}

// ---------------- per-node 1/count, centroid normalize ----------------
__global__ __launch_bounds__(256) void rcnt_kernel(const int* __restrict__ cnt, float* __restrict__ rcnt,
                                                   float* __restrict__ sumh, float* __restrict__ sumw) {
  int n = blockIdx.x * 256 + threadIdx.x;
  if (n >= NNODE) return;
  int c = cnt[n];
  float r = 1.0f / (float)(c > 1 ? c : 1);
  rcnt[n] = r;
  sumh[n] = sumh[n] * r * (1.0f / 255.0f);  // becomes pc_h
  sumw[n] = sumw[n] * r * (1.0f / 255.0f);  // becomes pc_w
}

// ---------------- fused 3-scale gather pooling ----------------
__device__ __forceinline__ float blo(uint u) { return __uint_as_float(u << 16); }
__device__ __forceinline__ float bhi(uint u) { return __uint_as_float(u & 0xffff0000u); }

__device__ __forceinline__ void accum_scale(const uint2* __restrict__ fb, int h, int w,
                                            int hs, float fh, int cp, float4& acc) {
  float ph = h * fh, pw = w * fh;
  int i0 = (int)ph, j0 = (int)pw;
  float th = ph - (float)i0, tw = pw - (float)j0;
  int i1 = min(i0 + 1, hs - 1), j1 = min(j0 + 1, hs - 1);
  const uint2* r0 = fb + (size_t)(i0 * hs) * 64 + cp;
  const uint2* r1 = fb + (size_t)(i1 * hs) * 64 + cp;
  uint2 u00 = r0[(size_t)j0 * 64], u01 = r0[(size_t)j1 * 64];
  uint2 u10 = r1[(size_t)j0 * 64], u11 = r1[(size_t)j1 * 64];
  float w11 = th * tw, w10 = th - w11, w01 = tw - w11, w00 = 1.f - th - tw + w11;
  acc.x += w00 * blo(u00.x) + w01 * blo(u01.x) + w10 * blo(u10.x) + w11 * blo(u11.x);
  acc.y += w00 * bhi(u00.x) + w01 * bhi(u01.x) + w10 * bhi(u10.x) + w11 * bhi(u11.x);
  acc.z += w00 * blo(u00.y) + w01 * blo(u01.y) + w10 * blo(u10.y) + w11 * blo(u11.y);
  acc.w += w00 * bhi(u00.y) + w01 * bhi(u01.y) + w10 * bhi(u10.y) + w11 * bhi(u11.y);
}

__global__ __launch_bounds__(256) void gather_pool_kernel(
    const uint2* __restrict__ F0, const uint2* __restrict__ F1, const uint2* __restrict__ F2,
    const int* __restrict__ poff, const int* __restrict__ psorted, const float* __restrict__ rc,
    float* __restrict__ p0, float* __restrict__ p1, float* __restrict__ p2) {
  int n = blockIdx.x;
  int t = threadIdx.x;
  int cp = t & 63;     // channel-quad (4 bf16 via uint2)
  int pg = t >> 6;     // 4 pixel streams
  int b = n >> 10;
  const uint2* f0 = F0 + (size_t)b * 1024 * 64;
  const uint2* f1 = F1 + (size_t)b * 4096 * 64;
  const uint2* f2 = F2 + (size_t)b * 16384 * 64;
  int j1e = poff[n + 1];
  float4 a0 = make_float4(0.f, 0.f, 0.f, 0.f);
  float4 a1 = a0, a2 = a0;
  int j = poff[n] + pg;
  int pnext = (j < j1e) ? psorted[j] : 0;
  while (j < j1e) {
    int p = pnext;
    j += 4;
    if (j < j1e) pnext = psorted[j];
    int h = (p >> 8) & 255, w = p & 255;
    accum_scale(f0, h, w, 32, 31.f / 255.f, cp, a0);
    accum_scale(f1, h, w, 64, 63.f / 255.f, cp, a1);
    accum_scale(f2, h, w, 128, 127.f / 255.f, cp, a2);
  }
  __shared__ float4 red[3][256];
  red[0][t] = a0; red[1][t] = a1; red[2][t] = a2;
  __syncthreads();
  if (t < 64) {
    float r = rc[n];
#pragma unroll
    for (int s = 0; s < 3; ++s) {
      float4 v0 = red[s][t], v1 = red[s][64 + t], v2 = red[s][128 + t], v3 = red[s][192 + t];
      float4 o;
      o.x = (v0.x + v1.x + v2.x + v3.x) * r;
      o.y = (v0.y + v1.y + v2.y + v3.y) * r;
      o.z = (v0.z + v1.z + v2.z + v3.z) * r;
      o.w = (v0.w + v1.w + v2.w + v3.w) * r;
      float* dst = (s == 0 ? p0 : (s == 1 ? p1 : p2));
      *(float4*)&dst[((size_t)n << 8) + 4 * t] = o;
    }
  }
}

// ---------------- edge attr (gaussian of centroid dist) ----------------
__global__ __launch_bounds__(256) void edge_attr_kernel(const int* __restrict__ src, const int* __restrict__ dst,
                                                        const float* __restrict__ pch, const float* __restrict__ pcw,
                                                        float* __restrict__ ew, float* __restrict__ outp) {
  int e = blockIdx.x * 256 + threadIdx.x;
  if (e >= EE) return;
  int s1 = src[e], d1 = dst[e];
  float dh = pch[s1] - pch[d1];
  float dw = pcw[s1] - pcw[d1];
  float ea = expf(-(dh * dh + dw * dw) * 20.0f);
  ew[e] = ea;
  outp[2 * EE + e] = ea;
}

// ---------------- mix: 0.5*x + 0.5*pool(normalized) ----------------
__global__ __launch_bounds__(256) void mix_kernel(const float* __restrict__ x, const float* __restrict__ p,
                                                  float* __restrict__ out) {
  int i = blockIdx.x * 256 + threadIdx.x;
  out[i] = 0.5f * (x[i] + p[i]);
}

// ---------------- CSR edge aggregation + bias + relu ----------------
__global__ __launch_bounds__(256) void agg_kernel(const float* __restrict__ h, const float* __restrict__ bias,
                                                  const int* __restrict__ eoff, const int* __restrict__ esorted,
                                                  const int* __restrict__ src, const float* __restrict__ ew,
                                                  float* __restrict__ xout) {
  int n = blockIdx.x;
  int c = threadIdx.x;
  int e0 = eoff[n], e1 = eoff[n + 1];
  float acc = 0.f;
  for (int j = e0; j < e1; ++j) {
    int e = esorted[j];
    acc += ew[e] * h[((size_t)src[e] << 8) + c];
  }
  float v = acc + bias[c];
  xout[((size_t)n << 8) + c] = v > 0.f ? v : 0.f;
}

// ---------------- score s = x @ lin_w ----------------
__global__ __launch_bounds__(256) void score_kernel(const float* __restrict__ x, const float* __restrict__ lw,
                                                    float* __restrict__ s) {
  int t = threadIdx.x;
  int n = blockIdx.x * 4 + (t >> 6);
  int lane = t & 63;
  const float* row = x + ((size_t)n << 8);
  float v = row[lane] * lw[lane] + row[lane + 64] * lw[lane + 64] +
            row[lane + 128] * lw[lane + 128] + row[lane + 192] * lw[lane + 192];
#pragma unroll
  for (int off = 32; off > 0; off >>= 1) v += __shfl_down(v, off, 64);
  if (lane == 0) s[n] = v;
}

// ---------------- final sigmoids ----------------
__global__ __launch_bounds__(256) void out_kernel(const float* __restrict__ s, const int* __restrict__ src,
                                                  const int* __restrict__ dst, const int* __restrict__ negs,
                                                  float* __restrict__ outp) {
  int e = blockIdx.x * 256 + threadIdx.x;
  if (e >= EE) return;
  float ss = s[src[e]];
  float a = ss - s[negs[e]];
  float b = ss - s[dst[e]];
  outp[e] = 1.0f / (1.0f + expf(-a));         // dan
  outp[EE + e] = 1.0f / (1.0f + expf(-b));    // dap
}

extern "C" void kernel_launch(void* const* d_in, const int* in_sizes, int n_in,
                              void* d_out, int out_size, void* d_ws, size_t ws_size,
                              hipStream_t stream) {
  const int*   labels = (const int*)d_in[0];
  const float* skip0  = (const float*)d_in[1];
  const float* skip1  = (const float*)d_in[2];
  const float* skip2  = (const float*)d_in[3];
  const int*   edges  = (const int*)d_in[4];
  const int*   negs   = (const int*)d_in[5];
  const float* W0     = (const float*)d_in[6];
  const float* b0     = (const float*)d_in[7];
  const float* W1     = (const float*)d_in[8];
  const float* b1     = (const float*)d_in[9];
  const float* W2     = (const float*)d_in[10];
  const float* b2     = (const float*)d_in[11];
  const float* lw     = (const float*)d_in[12];
  const int* esrc = edges;
  const int* edst = edges + EE;
  float* outp = (float*)d_out;

  // ---- workspace bump allocator (256B aligned) ----
  size_t o = 0;
  char* base = (char*)d_ws;
  auto alloc = [&](size_t bytes) -> void* {
    void* p = base + o;
    o += (bytes + 255) & ~(size_t)255;
    return p;
  };
  // zeroed block (must stay contiguous at front)
  int*   cnt   = (int*)alloc(NNODE * 4);
  float* sumh  = (float*)alloc(NNODE * 4);
  float* sumw  = (float*)alloc(NNODE * 4);
  int*   cnt_e = (int*)alloc(NNODE * 4);
  int*   ecur  = (int*)alloc(NNODE * 4);
  int*   pcur  = (int*)alloc(NNODE * 4);
  size_t zbytes = o;                  // 196,608 B
  // non-zeroed
  float* rcnt    = (float*)alloc(NNODE * 4);
  int*   eoff    = (int*)alloc((NNODE + 1) * 4);
  int*   poff    = (int*)alloc((NNODE + 1) * 4);
  int*   esorted = (int*)alloc(EE * 4);
  int*   psorted = (int*)alloc(NPIX * 4);
  float* ewb     = (float*)alloc(EE * 4);
  int*   segb    = (int*)alloc(NPIX * 4);
  float* bufA    = (float*)alloc((size_t)NNODE * CH * 4);
  float* bufB    = (float*)alloc((size_t)NNODE * CH * 4);
  float* bufC    = (float*)alloc((size_t)NNODE * CH * 4);
  float* F0f     = (float*)bufB;      // [8192][512] fp32 overlay on bufB+bufC (16MB), dead before bufB written
  float* F0t32   = (float*)bufA;      // [8192][256] fp32 overlay on bufA, dead after cvt
  uint*  F0b     = (uint*)alloc((size_t)BB * 1024 * CH * 2);       // 4 MB bf16
  uint*  F1t     = (uint*)alloc((size_t)BB * 4096 * CH * 2);       // 16.8 MB
  uint*  F2t     = (uint*)alloc((size_t)BB * 16384 * CH * 2);      // 67 MB
  float* p1buf   = (float*)alloc((size_t)NNODE * CH * 4);
  float* p2buf   = (float*)alloc((size_t)NNODE * CH * 4);
  float* sbuf    = (float*)alloc(NNODE * 4);
  (void)ws_size; (void)n_in; (void)in_sizes; (void)out_size;

  // 1. zero accumulators
  zero_kernel<<<64, 256, 0, stream>>>((int4*)d_ws, (int)(zbytes / 16));
  // 2. seg ids + counts + coord sums
  seg_cnt_kernel<<<NPIX / 256, 256, 0, stream>>>(labels, segb, cnt, sumh, sumw);
  // 3-4. pixel CSR by seg
  scan_kernel<<<1, 1024, 0, stream>>>(cnt, poff);
  pixel_scatter_kernel<<<NPIX / 256, 256, 0, stream>>>(segb, poff, pcur, psorted);
  // 5-7. edge CSR by dst
  edge_cnt_kernel<<<EE / 256, 256, 0, stream>>>(edst, cnt_e);
  scan_kernel<<<1, 1024, 0, stream>>>(cnt_e, eoff);
  edge_scatter_kernel<<<EE / 256, 256, 0, stream>>>(edst, eoff, ecur, esorted);
  // 8. skip0 -> channels-last fp32 [8192][512]
  transpose_cl<float><<<dim3(1024 / 32, 512 / 32, BB), dim3(32, 8), 0, stream>>>(skip0, F0f, 512, 1024);
  // 9. fold W0: F0t32 = F0f @ W0   [8192x512]@[512x256]
  gemm_n256<<<NNODE / 16, 256, 0, stream>>>(F0f, W0, F0t32, 512);
  // 10. F0t32 -> bf16
  cvt_bf16_kernel<<<(NNODE * CH / 2) / 256, 256, 0, stream>>>((const float2*)F0t32, F0b, NNODE * CH / 2);
  // 11-12. skip1/skip2 -> channels-last bf16
  transpose_cl<bf16><<<dim3(4096 / 32, 256 / 32, BB), dim3(32, 8), 0, stream>>>(skip1, (bf16*)F1t, 256, 4096);
  transpose_cl<bf16><<<dim3(16384 / 32, 256 / 32, BB), dim3(32, 8), 0, stream>>>(skip2, (bf16*)F2t, 256, 16384);
  // 13. 1/cnt + centroids
  rcnt_kernel<<<NNODE / 256, 256, 0, stream>>>(cnt, rcnt, sumh, sumw);
  // 14. fused 3-scale gather pooling (normalized outputs)
  gather_pool_kernel<<<NNODE, 256, 0, stream>>>((const uint2*)F0b, (const uint2*)F1t, (const uint2*)F2t,
                                                poff, psorted, rcnt, bufA, p1buf, p2buf);
  // 15. edge weights + output edge_attr
  edge_attr_kernel<<<EE / 256, 256, 0, stream>>>(esrc, edst, sumh, sumw, ewb, outp);
  // 16. layer0 aggregate -> x1
  agg_kernel<<<NNODE, 256, 0, stream>>>(bufA, b0, eoff, esorted, esrc, ewb, bufB);
  // 17-19. layer1
  mix_kernel<<<(NNODE * CH) / 256, 256, 0, stream>>>(bufB, p1buf, bufC);
  gemm_n256<<<NNODE / 16, 256, 0, stream>>>(bufC, W1, bufA, 256);
  agg_kernel<<<NNODE, 256, 0, stream>>>(bufA, b1, eoff, esorted, esrc, ewb, bufB);
  // 20-22. layer2
  mix_kernel<<<(NNODE * CH) / 256, 256, 0, stream>>>(bufB, p2buf, bufC);
  gemm_n256<<<NNODE / 16, 256, 0, stream>>>(bufC, W2, bufA, 256);
  agg_kernel<<<NNODE, 256, 0, stream>>>(bufA, b2, eoff, esorted, esrc, ewb, bufB);
  // 23. s = x3 @ lin_w
  score_kernel<<<NNODE / 4, 256, 0, stream>>>(bufB, lw, sbuf);
  // 24. dan / dap
  out_kernel<<<EE / 256, 256, 0, stream>>>(sbuf, esrc, edst, negs, outp);
}

// Round 3
// 863.620 us; speedup vs baseline: 2.3266x; 1.1881x over previous
//
#include <hip/hip_runtime.h>
#include <hip/hip_bf16.h>
#include <cstdint>
#include <cstddef>

#define BB 8
#define NSPX 1024
#define NNODE 8192      // BB*NSPX
#define EE 131072
#define NPIX 524288     // BB*256*256
#define CH 256

using bf16 = __hip_bfloat16;
typedef unsigned int uint;
typedef unsigned long long u64;

__device__ __forceinline__ float blo(uint u) { return __uint_as_float(u << 16); }
__device__ __forceinline__ float bhi(uint u) { return __uint_as_float(u & 0xffff0000u); }

// ---------------- zero workspace accumulators ----------------
__global__ __launch_bounds__(256) void zero_kernel(int4* p, int n4) {
  int i = blockIdx.x * 256 + threadIdx.x;
  int stride = gridDim.x * 256;
  int4 z = make_int4(0, 0, 0, 0);
  for (; i < n4; i += stride) p[i] = z;
}

// ---------------- seg ids + packed (cnt,sumh,sumw) atomics ----------------
__global__ __launch_bounds__(256) void seg_cnt_kernel(const int* __restrict__ labels,
                                                      int* __restrict__ segb,
                                                      u64* __restrict__ packed) {
  int p = blockIdx.x * 256 + threadIdx.x;
  if (p >= NPIX) return;
  int b = p >> 16;
  int h = (p >> 8) & 255;
  int w = p & 255;
  int seg = labels[p] + (b << 10);
  segb[p] = seg;
  u64 enc = (1ULL << 48) | ((u64)h << 24) | (u64)w;
  atomicAdd(&packed[seg], enc);
}

// ---------------- decode counts, centroids ----------------
__global__ __launch_bounds__(256) void rcnt_kernel(const u64* __restrict__ packed,
                                                   int* __restrict__ cnt, float* __restrict__ rcnt,
                                                   float* __restrict__ pch, float* __restrict__ pcw) {
  int n = blockIdx.x * 256 + threadIdx.x;
  if (n >= NNODE) return;
  u64 v = packed[n];
  int c = (int)(v >> 48);
  int sh = (int)((v >> 24) & 0xFFFFFF);
  int sw = (int)(v & 0xFFFFFF);
  cnt[n] = c;
  float r = 1.0f / (float)(c > 1 ? c : 1);
  rcnt[n] = r;
  pch[n] = (float)sh * r * (1.0f / 255.0f);
  pcw[n] = (float)sw * r * (1.0f / 255.0f);
}

// ---------------- generic 8192-length exclusive scan (1 block) ----------------
__global__ __launch_bounds__(1024) void scan_kernel(const int* __restrict__ cin, int* __restrict__ coff) {
  __shared__ int ps[1024];
  int t = threadIdx.x;
  int base = t * 8;
  int v[8];
  int sum = 0;
#pragma unroll
  for (int i = 0; i < 8; ++i) {
    int x = cin[base + i];
    v[i] = sum;
    sum += x;
  }
  ps[t] = sum;
  __syncthreads();
  for (int off = 1; off < 1024; off <<= 1) {
    int x = (t >= off) ? ps[t - off] : 0;
    __syncthreads();
    ps[t] += x;
    __syncthreads();
  }
  int prev = (t == 0) ? 0 : ps[t - 1];
#pragma unroll
  for (int i = 0; i < 8; ++i) coff[base + i] = prev + v[i];
  if (t == 1023) coff[8192] = ps[1023];
}

// ---------------- edge counting sort by dst ----------------
__global__ __launch_bounds__(256) void edge_cnt_kernel(const int* __restrict__ dst, int* __restrict__ cnt_e) {
  int e = blockIdx.x * 256 + threadIdx.x;
  if (e < EE) atomicAdd(&cnt_e[dst[e]], 1);
}

__global__ __launch_bounds__(256) void edge_scatter_kernel(const int* __restrict__ dst,
                                                           const int* __restrict__ eoff,
                                                           int* __restrict__ ecur,
                                                           int* __restrict__ esorted) {
  int e = blockIdx.x * 256 + threadIdx.x;
  if (e >= EE) return;
  int d = dst[e];
  int pos = eoff[d] + atomicAdd(&ecur[d], 1);
  esorted[pos] = e;
}

// ---------------- pixel counting sort by seg ----------------
__global__ __launch_bounds__(256) void pixel_scatter_kernel(const int* __restrict__ segb,
                                                            const int* __restrict__ poff,
                                                            int* __restrict__ pcur,
                                                            int* __restrict__ psorted) {
  int p = blockIdx.x * 256 + threadIdx.x;
  if (p >= NPIX) return;
  int s = segb[p];
  int pos = poff[s] + atomicAdd(&pcur[s], 1);
  psorted[pos] = p;
}

// ---------------- skip0 fold: out[b][m][n] = sum_k skip0[b][k][m] * W0[k][n], bf16 out ----
// A is K-major per frame: [512][1024]. Grid: (16 Mtiles, 2 Ntiles(128), 8 frames)
__global__ __launch_bounds__(256) void gemm_kmaj_bf16(const float* __restrict__ A,
                                                      const float* __restrict__ W,
                                                      bf16* __restrict__ out) {
  __shared__ float As[64][65];
  int b = blockIdx.z;
  int m0 = blockIdx.x * 64;
  int n0 = blockIdx.y * 128;
  int t = threadIdx.x;
  int ct = t & 31, rt = t >> 5;      // 32 n-quads x 8 row-groups
  int l16 = t & 15, kr = t >> 4;     // staging: 16 m-quads x 16 k-rows
  const float* Ab = A + (size_t)b * 512 * 1024;
  float4 acc[8];
#pragma unroll
  for (int i = 0; i < 8; ++i) acc[i] = make_float4(0.f, 0.f, 0.f, 0.f);
  for (int k0 = 0; k0 < 512; k0 += 64) {
#pragma unroll
    for (int pass = 0; pass < 4; ++pass) {
      int k = kr + pass * 16;
      float4 v = *(const float4*)&Ab[(size_t)(k0 + k) * 1024 + m0 + l16 * 4];
      As[k][l16 * 4 + 0] = v.x;
      As[k][l16 * 4 + 1] = v.y;
      As[k][l16 * 4 + 2] = v.z;
      As[k][l16 * 4 + 3] = v.w;
    }
    __syncthreads();
#pragma unroll 8
    for (int k = 0; k < 64; ++k) {
      float4 wv = *(const float4*)&W[(size_t)(k0 + k) * 256 + n0 + ct * 4];
#pragma unroll
      for (int i = 0; i < 8; ++i) {
        float a = As[k][rt * 8 + i];
        acc[i].x += a * wv.x;
        acc[i].y += a * wv.y;
        acc[i].z += a * wv.z;
        acc[i].w += a * wv.w;
      }
    }
    __syncthreads();
  }
#pragma unroll
  for (int i = 0; i < 8; ++i) {
    int m = m0 + rt * 8 + i;
    __hip_bfloat162 lo = __float22bfloat162_rn(make_float2(acc[i].x, acc[i].y));
    __hip_bfloat162 hi = __float22bfloat162_rn(make_float2(acc[i].z, acc[i].w));
    uint2 pk = make_uint2(*reinterpret_cast<uint*>(&lo), *reinterpret_cast<uint*>(&hi));
    *(uint2*)&out[((size_t)b * 1024 + m) * 256 + n0 + ct * 4] = pk;
  }
}

// ---------------- transpose [B,C,P] -> [B,P,C] bf16, 64x64 tile, 16B stores ----------------
__global__ __launch_bounds__(256) void transpose64_bf16(const float* __restrict__ src, bf16* __restrict__ dst,
                                                        int C, int P) {
  __shared__ float tile[64][65];
  int b = blockIdx.z;
  int p0 = blockIdx.x * 64;
  int c0 = blockIdx.y * 64;
  int t = threadIdx.x;
  int l16 = t & 15, r16 = t >> 4;
#pragma unroll
  for (int pass = 0; pass < 4; ++pass) {
    int c = r16 + pass * 16;
    float4 v = *(const float4*)&src[((size_t)b * C + c0 + c) * P + p0 + l16 * 4];
    tile[c][l16 * 4 + 0] = v.x;
    tile[c][l16 * 4 + 1] = v.y;
    tile[c][l16 * 4 + 2] = v.z;
    tile[c][l16 * 4 + 3] = v.w;
  }
  __syncthreads();
  int l8 = t & 7, r32 = t >> 3;
#pragma unroll
  for (int pass = 0; pass < 2; ++pass) {
    int p = r32 + pass * 32;
    uint r[4];
#pragma unroll
    for (int q = 0; q < 4; ++q) {
      __hip_bfloat162 h2 = __float22bfloat162_rn(make_float2(tile[l8 * 8 + 2 * q][p], tile[l8 * 8 + 2 * q + 1][p]));
      r[q] = *reinterpret_cast<uint*>(&h2);
    }
    *(uint4*)&dst[((size_t)b * P + p0 + p) * C + c0 + l8 * 8] = make_uint4(r[0], r[1], r[2], r[3]);
  }
}

// ---------------- per-scale gather pooling, XCD frame affinity ----------------
__device__ __forceinline__ void accum8(float wt, uint4 u, float* a) {
  a[0] += wt * blo(u.x); a[1] += wt * bhi(u.x);
  a[2] += wt * blo(u.y); a[3] += wt * bhi(u.y);
  a[4] += wt * blo(u.z); a[5] += wt * bhi(u.z);
  a[6] += wt * blo(u.w); a[7] += wt * bhi(u.w);
}

template <int HS, int LPP>
__global__ __launch_bounds__(256) void gather_scale(const bf16* __restrict__ F,
                                                    const int* __restrict__ poff,
                                                    const int* __restrict__ psorted,
                                                    const float* __restrict__ rc,
                                                    float* __restrict__ pout) {
  constexpr int S = 256 / LPP;      // pixel streams
  constexpr int CHUNK = LPP * 8;    // channels this dispatch-slice
  int blk = blockIdx.x;
  int n = ((blk & 7) << 10) | (blk >> 3);   // frame f -> XCD f (round-robin heuristic)
  int b = n >> 10;
  int c0 = blockIdx.y * CHUNK;
  int t = threadIdx.x;
  int l = t & (LPP - 1);
  int s = t / LPP;
  const bf16* fb = F + (size_t)b * (HS * HS) * 256 + c0 + l * 8;
  const float fh = (float)(HS - 1) / 255.0f;
  int j1 = poff[n + 1];
  float acc[8];
#pragma unroll
  for (int i = 0; i < 8; ++i) acc[i] = 0.f;
  for (int j = poff[n] + s; j < j1; j += S) {
    int p = psorted[j];
    int h = (p >> 8) & 255, w = p & 255;
    float ph = h * fh, pw = w * fh;
    int i0 = (int)ph, j0 = (int)pw;
    float th = ph - (float)i0, tw = pw - (float)j0;
    int i1 = min(i0 + 1, HS - 1), jj1 = min(j0 + 1, HS - 1);
    float w11 = th * tw, w10 = th - w11, w01 = tw - w11, w00 = 1.f - th - tw + w11;
    uint4 u00 = *(const uint4*)(fb + (i0 * HS + j0) * 256);
    uint4 u01 = *(const uint4*)(fb + (i0 * HS + jj1) * 256);
    uint4 u10 = *(const uint4*)(fb + (i1 * HS + j0) * 256);
    uint4 u11 = *(const uint4*)(fb + (i1 * HS + jj1) * 256);
    accum8(w00, u00, acc);
    accum8(w01, u01, acc);
    accum8(w10, u10, acc);
    accum8(w11, u11, acc);
  }
  __shared__ float4 red4[512];
  red4[t * 2 + 0] = make_float4(acc[0], acc[1], acc[2], acc[3]);
  red4[t * 2 + 1] = make_float4(acc[4], acc[5], acc[6], acc[7]);
  __syncthreads();
  if (t < LPP * 2) {
    float r = rc[n];
    int l2 = t >> 1, half = t & 1;
    float4 sum = make_float4(0.f, 0.f, 0.f, 0.f);
#pragma unroll
    for (int ss = 0; ss < S; ++ss) {
      float4 v = red4[(ss * LPP + l2) * 2 + half];
      sum.x += v.x; sum.y += v.y; sum.z += v.z; sum.w += v.w;
    }
    sum.x *= r; sum.y *= r; sum.z *= r; sum.w *= r;
    *(float4*)&pout[(size_t)n * 256 + c0 + t * 4] = sum;
  }
}

// ---------------- edge attr (gaussian of centroid dist) ----------------
__global__ __launch_bounds__(256) void edge_attr_kernel(const int* __restrict__ src, const int* __restrict__ dst,
                                                        const float* __restrict__ pch, const float* __restrict__ pcw,
                                                        float* __restrict__ ew, float* __restrict__ outp) {
  int e = blockIdx.x * 256 + threadIdx.x;
  if (e >= EE) return;
  int s1 = src[e], d1 = dst[e];
  float dh = pch[s1] - pch[d1];
  float dw = pcw[s1] - pcw[d1];
  float ea = expf(-(dh * dh + dw * dw) * 20.0f);
  ew[e] = ea;
  outp[2 * EE + e] = ea;
}

// ---------------- GEMM with fused mix: out = (0.5*(X+P)) @ W, K=N=256 ----------------
__global__ __launch_bounds__(256) void gemm_mix_n256(const float* __restrict__ X, const float* __restrict__ Pl,
                                                     const float* __restrict__ W, float* __restrict__ out) {
  const int t = threadIdx.x;
  const int r0 = blockIdx.x * 16;
  const int cw = (t & 63) * 4;
  const int rg = (t >> 6) * 4;
  __shared__ float Xl[16][68];
  float4 acc[4];
#pragma unroll
  for (int i = 0; i < 4; ++i) acc[i] = make_float4(0.f, 0.f, 0.f, 0.f);
  for (int k0 = 0; k0 < 256; k0 += 64) {
#pragma unroll
    for (int l = 0; l < 4; ++l) {
      int idx = t + 256 * l;
      int r = idx >> 6, k = idx & 63;
      size_t a = (size_t)(r0 + r) * 256 + k0 + k;
      Xl[r][k] = 0.5f * (X[a] + Pl[a]);
    }
    __syncthreads();
#pragma unroll
    for (int k4 = 0; k4 < 64; k4 += 4) {
      float4 a[4];
#pragma unroll
      for (int i = 0; i < 4; ++i) a[i] = *(const float4*)&Xl[rg + i][k4];
#pragma unroll
      for (int kk = 0; kk < 4; ++kk) {
        float4 w = *(const float4*)&W[(size_t)(k0 + k4 + kk) * 256 + cw];
#pragma unroll
        for (int i = 0; i < 4; ++i) {
          float av = ((const float*)&a[i])[kk];
          acc[i].x += av * w.x;
          acc[i].y += av * w.y;
          acc[i].z += av * w.z;
          acc[i].w += av * w.w;
        }
      }
    }
    __syncthreads();
  }
#pragma unroll
  for (int i = 0; i < 4; ++i)
    *(float4*)&out[(size_t)(r0 + rg + i) * 256 + cw] = acc[i];
}

// ---------------- CSR edge aggregation + bias + relu ----------------
__global__ __launch_bounds__(256) void agg_kernel(const float* __restrict__ h, const float* __restrict__ bias,
                                                  const int* __restrict__ eoff, const int* __restrict__ esorted,
                                                  const int* __restrict__ src, const float* __restrict__ ew,
                                                  float* __restrict__ xout) {
  int n = blockIdx.x;
  int c = threadIdx.x;
  int e0 = eoff[n], e1 = eoff[n + 1];
  float acc = 0.f;
  for (int j = e0; j < e1; ++j) {
    int e = esorted[j];
    acc += ew[e] * h[((size_t)src[e] << 8) + c];
  }
  float v = acc + bias[c];
  xout[((size_t)n << 8) + c] = v > 0.f ? v : 0.f;
}

// ---------------- score s = x @ lin_w ----------------
__global__ __launch_bounds__(256) void score_kernel(const float* __restrict__ x, const float* __restrict__ lw,
                                                    float* __restrict__ s) {
  int t = threadIdx.x;
  int n = blockIdx.x * 4 + (t >> 6);
  int lane = t & 63;
  const float* row = x + ((size_t)n << 8);
  float v = row[lane] * lw[lane] + row[lane + 64] * lw[lane + 64] +
            row[lane + 128] * lw[lane + 128] + row[lane + 192] * lw[lane + 192];
#pragma unroll
  for (int off = 32; off > 0; off >>= 1) v += __shfl_down(v, off, 64);
  if (lane == 0) s[n] = v;
}

// ---------------- final sigmoids ----------------
__global__ __launch_bounds__(256) void out_kernel(const float* __restrict__ s, const int* __restrict__ src,
                                                  const int* __restrict__ dst, const int* __restrict__ negs,
                                                  float* __restrict__ outp) {
  int e = blockIdx.x * 256 + threadIdx.x;
  if (e >= EE) return;
  float ss = s[src[e]];
  float a = ss - s[negs[e]];
  float b = ss - s[dst[e]];
  outp[e] = 1.0f / (1.0f + expf(-a));         // dan
  outp[EE + e] = 1.0f / (1.0f + expf(-b));    // dap
}

extern "C" void kernel_launch(void* const* d_in, const int* in_sizes, int n_in,
                              void* d_out, int out_size, void* d_ws, size_t ws_size,
                              hipStream_t stream) {
  const int*   labels = (const int*)d_in[0];
  const float* skip0  = (const float*)d_in[1];
  const float* skip1  = (const float*)d_in[2];
  const float* skip2  = (const float*)d_in[3];
  const int*   edges  = (const int*)d_in[4];
  const int*   negs   = (const int*)d_in[5];
  const float* W0     = (const float*)d_in[6];
  const float* b0     = (const float*)d_in[7];
  const float* W1     = (const float*)d_in[8];
  const float* b1     = (const float*)d_in[9];
  const float* W2     = (const float*)d_in[10];
  const float* b2     = (const float*)d_in[11];
  const float* lw     = (const float*)d_in[12];
  const int* esrc = edges;
  const int* edst = edges + EE;
  float* outp = (float*)d_out;

  // ---- workspace bump allocator (256B aligned) ----
  size_t o = 0;
  char* base = (char*)d_ws;
  auto alloc = [&](size_t bytes) -> void* {
    void* p = base + o;
    o += (bytes + 255) & ~(size_t)255;
    return p;
  };
  // zeroed block (contiguous at front)
  u64* packed  = (u64*)alloc(NNODE * 8);
  int* cnt_e   = (int*)alloc(NNODE * 4);
  int* ecur    = (int*)alloc(NNODE * 4);
  int* pcur    = (int*)alloc(NNODE * 4);
  size_t zbytes = o;
  // non-zeroed
  int*   cntp    = (int*)alloc(NNODE * 4);
  float* rcnt    = (float*)alloc(NNODE * 4);
  float* pch     = (float*)alloc(NNODE * 4);
  float* pcw     = (float*)alloc(NNODE * 4);
  int*   poff    = (int*)alloc((NNODE + 1) * 4);
  int*   eoff    = (int*)alloc((NNODE + 1) * 4);
  int*   esorted = (int*)alloc(EE * 4);
  int*   psorted = (int*)alloc(NPIX * 4);
  float* ewb     = (float*)alloc(EE * 4);
  int*   segb    = (int*)alloc(NPIX * 4);
  float* bufA    = (float*)alloc((size_t)NNODE * CH * 4);
  float* bufB    = (float*)alloc((size_t)NNODE * CH * 4);
  float* bufC    = (float*)alloc((size_t)NNODE * CH * 4);
  float* p1buf   = (float*)alloc((size_t)NNODE * CH * 4);
  float* p2buf   = (float*)alloc((size_t)NNODE * CH * 4);
  bf16*  F0b     = (bf16*)alloc((size_t)BB * 1024 * CH * 2);   // 4 MB
  bf16*  F1t     = (bf16*)alloc((size_t)BB * 4096 * CH * 2);   // 16.8 MB
  bf16*  F2t     = (bf16*)alloc((size_t)BB * 16384 * CH * 2);  // 67 MB
  float* sbuf    = (float*)alloc(NNODE * 4);
  (void)ws_size; (void)n_in; (void)in_sizes; (void)out_size;

  // 1. zero accumulators
  zero_kernel<<<64, 256, 0, stream>>>((int4*)d_ws, (int)(zbytes / 16));
  // 2. seg ids + packed count/coord atomics
  seg_cnt_kernel<<<NPIX / 256, 256, 0, stream>>>(labels, segb, packed);
  // 3. decode counts + centroids
  rcnt_kernel<<<NNODE / 256, 256, 0, stream>>>(packed, cntp, rcnt, pch, pcw);
  // 4-5. pixel CSR by seg
  scan_kernel<<<1, 1024, 0, stream>>>(cntp, poff);
  pixel_scatter_kernel<<<NPIX / 256, 256, 0, stream>>>(segb, poff, pcur, psorted);
  // 6-8. edge CSR by dst
  edge_cnt_kernel<<<EE / 256, 256, 0, stream>>>(edst, cnt_e);
  scan_kernel<<<1, 1024, 0, stream>>>(cnt_e, eoff);
  edge_scatter_kernel<<<EE / 256, 256, 0, stream>>>(edst, eoff, ecur, esorted);
  // 9. skip0 @ W0 -> F0b (bf16, channels-last), direct from channel-first
  gemm_kmaj_bf16<<<dim3(16, 2, BB), 256, 0, stream>>>(skip0, W0, F0b);
  // 10-11. skip1/skip2 -> channels-last bf16
  transpose64_bf16<<<dim3(4096 / 64, 4, BB), 256, 0, stream>>>(skip1, F1t, 256, 4096);
  transpose64_bf16<<<dim3(16384 / 64, 4, BB), 256, 0, stream>>>(skip2, F2t, 256, 16384);
  // 12-14. per-scale gather pooling (normalized outputs), XCD frame affinity
  gather_scale<32, 32><<<dim3(NNODE, 1), 256, 0, stream>>>(F0b, poff, psorted, rcnt, bufA);
  gather_scale<64, 32><<<dim3(NNODE, 1), 256, 0, stream>>>(F1t, poff, psorted, rcnt, p1buf);
  gather_scale<128, 16><<<dim3(NNODE, 2), 256, 0, stream>>>(F2t, poff, psorted, rcnt, p2buf);
  // 15. edge weights + output edge_attr
  edge_attr_kernel<<<EE / 256, 256, 0, stream>>>(esrc, edst, pch, pcw, ewb, outp);
  // 16. layer0 aggregate -> x1
  agg_kernel<<<NNODE, 256, 0, stream>>>(bufA, b0, eoff, esorted, esrc, ewb, bufB);
  // 17-18. layer1 (mix fused into GEMM)
  gemm_mix_n256<<<NNODE / 16, 256, 0, stream>>>(bufB, p1buf, W1, bufC);
  agg_kernel<<<NNODE, 256, 0, stream>>>(bufC, b1, eoff, esorted, esrc, ewb, bufA);
  // 19-20. layer2
  gemm_mix_n256<<<NNODE / 16, 256, 0, stream>>>(bufA, p2buf, W2, bufC);
  agg_kernel<<<NNODE, 256, 0, stream>>>(bufC, b2, eoff, esorted, esrc, ewb, bufB);
  // 21. s = x3 @ lin_w
  score_kernel<<<NNODE / 4, 256, 0, stream>>>(bufB, lw, sbuf);
  // 22. dan / dap
  out_kernel<<<EE / 256, 256, 0, stream>>>(sbuf, esrc, edst, negs, outp);
}

// Round 4
// 774.682 us; speedup vs baseline: 2.5937x; 1.1148x over previous
//
#include <hip/hip_runtime.h>
#include <hip/hip_bf16.h>
#include <cstdint>
#include <cstddef>

#define BB 8
#define NSPX 1024
#define NNODE 8192      // BB*NSPX
#define EE 131072
#define NPIX 524288     // BB*256*256
#define CH 256

using bf16 = __hip_bfloat16;
typedef unsigned int uint;
typedef unsigned long long u64;

__device__ __forceinline__ float blo(uint u) { return __uint_as_float(u << 16); }
__device__ __forceinline__ float bhi(uint u) { return __uint_as_float(u & 0xffff0000u); }

// ---------------- zero workspace accumulators ----------------
__global__ __launch_bounds__(256) void zero_kernel(int4* p, int n4) {
  int i = blockIdx.x * 256 + threadIdx.x;
  int stride = gridDim.x * 256;
  int4 z = make_int4(0, 0, 0, 0);
  for (; i < n4; i += stride) p[i] = z;
}

// ---------------- seg ids + packed (cnt,sumh,sumw) atomics ----------------
__global__ __launch_bounds__(256) void seg_cnt_kernel(const int* __restrict__ labels,
                                                      int* __restrict__ segb,
                                                      u64* __restrict__ packed) {
  int p = blockIdx.x * 256 + threadIdx.x;
  if (p >= NPIX) return;
  int b = p >> 16;
  int h = (p >> 8) & 255;
  int w = p & 255;
  int seg = labels[p] + (b << 10);
  segb[p] = seg;
  u64 enc = (1ULL << 48) | ((u64)h << 24) | (u64)w;
  atomicAdd(&packed[seg], enc);
}

// ---------------- decode counts, centroids ----------------
__global__ __launch_bounds__(256) void rcnt_kernel(const u64* __restrict__ packed,
                                                   int* __restrict__ cnt, float* __restrict__ rcnt,
                                                   float* __restrict__ pch, float* __restrict__ pcw) {
  int n = blockIdx.x * 256 + threadIdx.x;
  if (n >= NNODE) return;
  u64 v = packed[n];
  int c = (int)(v >> 48);
  int sh = (int)((v >> 24) & 0xFFFFFF);
  int sw = (int)(v & 0xFFFFFF);
  cnt[n] = c;
  float r = 1.0f / (float)(c > 1 ? c : 1);
  rcnt[n] = r;
  pch[n] = (float)sh * r * (1.0f / 255.0f);
  pcw[n] = (float)sw * r * (1.0f / 255.0f);
}

// ---------------- generic 8192-length exclusive scan (1 block) ----------------
__global__ __launch_bounds__(1024) void scan_kernel(const int* __restrict__ cin, int* __restrict__ coff) {
  __shared__ int ps[1024];
  int t = threadIdx.x;
  int base = t * 8;
  int v[8];
  int sum = 0;
#pragma unroll
  for (int i = 0; i < 8; ++i) {
    int x = cin[base + i];
    v[i] = sum;
    sum += x;
  }
  ps[t] = sum;
  __syncthreads();
  for (int off = 1; off < 1024; off <<= 1) {
    int x = (t >= off) ? ps[t - off] : 0;
    __syncthreads();
    ps[t] += x;
    __syncthreads();
  }
  int prev = (t == 0) ? 0 : ps[t - 1];
#pragma unroll
  for (int i = 0; i < 8; ++i) coff[base + i] = prev + v[i];
  if (t == 1023) coff[8192] = ps[1023];
}

// ---------------- edge counting sort by dst ----------------
__global__ __launch_bounds__(256) void edge_cnt_kernel(const int* __restrict__ dst, int* __restrict__ cnt_e) {
  int e = blockIdx.x * 256 + threadIdx.x;
  if (e < EE) atomicAdd(&cnt_e[dst[e]], 1);
}

// ---------------- edge attr (gaussian of centroid dist), before scatter ----------------
__global__ __launch_bounds__(256) void edge_attr_kernel(const int* __restrict__ src, const int* __restrict__ dst,
                                                        const float* __restrict__ pch, const float* __restrict__ pcw,
                                                        float* __restrict__ ew, float* __restrict__ outp) {
  int e = blockIdx.x * 256 + threadIdx.x;
  if (e >= EE) return;
  int s1 = src[e], d1 = dst[e];
  float dh = pch[s1] - pch[d1];
  float dw = pcw[s1] - pcw[d1];
  float ea = expf(-(dh * dh + dw * dw) * 20.0f);
  ew[e] = ea;
  outp[2 * EE + e] = ea;
}

// ---------------- edge scatter: emit CSR-ordered (src, ew) directly ----------------
__global__ __launch_bounds__(256) void edge_scatter_kernel(const int* __restrict__ dst,
                                                           const int* __restrict__ src,
                                                           const float* __restrict__ ew,
                                                           const int* __restrict__ eoff,
                                                           int* __restrict__ ecur,
                                                           int* __restrict__ srcs,
                                                           float* __restrict__ ews) {
  int e = blockIdx.x * 256 + threadIdx.x;
  if (e >= EE) return;
  int d = dst[e];
  int pos = eoff[d] + atomicAdd(&ecur[d], 1);
  srcs[pos] = src[e];
  ews[pos] = ew[e];
}

// ---------------- pixel counting sort by seg ----------------
__global__ __launch_bounds__(256) void pixel_scatter_kernel(const int* __restrict__ segb,
                                                            const int* __restrict__ poff,
                                                            int* __restrict__ pcur,
                                                            int* __restrict__ psorted) {
  int p = blockIdx.x * 256 + threadIdx.x;
  if (p >= NPIX) return;
  int s = segb[p];
  int pos = poff[s] + atomicAdd(&pcur[s], 1);
  psorted[pos] = p;
}

// ---------------- skip0 fold: out[b][m][n] = sum_k skip0[b][k][m] * W0[k][n], bf16 out ----
// A K-major per frame [512][1024]. Grid: (32 Mtiles(32), 2 Ntiles(128), 8 frames) = 512 blocks
__global__ __launch_bounds__(256) void gemm_kmaj_bf16(const float* __restrict__ A,
                                                      const float* __restrict__ W,
                                                      bf16* __restrict__ out) {
  __shared__ float As[64][36];   // 64 k x 32 m, row stride 36 (16B-aligned, bank-spread)
  int b = blockIdx.z;
  int m0 = blockIdx.x * 32;
  int n0 = blockIdx.y * 128;
  int t = threadIdx.x;
  int ct = t & 31;               // n-quad: n = n0 + ct*4
  int rm = t >> 5;               // m-group: rows rm*4 .. rm*4+3
  int l8 = t & 7, kr = t >> 3;   // staging: 8 m-quads x 32 k-rows
  const float* Ab = A + (size_t)b * 512 * 1024;
  float4 acc[4];
#pragma unroll
  for (int i = 0; i < 4; ++i) acc[i] = make_float4(0.f, 0.f, 0.f, 0.f);
  for (int k0 = 0; k0 < 512; k0 += 64) {
#pragma unroll
    for (int pass = 0; pass < 2; ++pass) {
      int k = kr + pass * 32;
      float4 v = *(const float4*)&Ab[(size_t)(k0 + k) * 1024 + m0 + l8 * 4];
      *(float4*)&As[k][l8 * 4] = v;
    }
    __syncthreads();
#pragma unroll 8
    for (int k = 0; k < 64; ++k) {
      float4 a = *(const float4*)&As[k][rm * 4];
      float4 wv = *(const float4*)&W[(size_t)(k0 + k) * 256 + n0 + ct * 4];
      acc[0].x += a.x * wv.x; acc[0].y += a.x * wv.y; acc[0].z += a.x * wv.z; acc[0].w += a.x * wv.w;
      acc[1].x += a.y * wv.x; acc[1].y += a.y * wv.y; acc[1].z += a.y * wv.z; acc[1].w += a.y * wv.w;
      acc[2].x += a.z * wv.x; acc[2].y += a.z * wv.y; acc[2].z += a.z * wv.z; acc[2].w += a.z * wv.w;
      acc[3].x += a.w * wv.x; acc[3].y += a.w * wv.y; acc[3].z += a.w * wv.z; acc[3].w += a.w * wv.w;
    }
    __syncthreads();
  }
#pragma unroll
  for (int i = 0; i < 4; ++i) {
    int m = m0 + rm * 4 + i;
    __hip_bfloat162 lo = __float22bfloat162_rn(make_float2(acc[i].x, acc[i].y));
    __hip_bfloat162 hi = __float22bfloat162_rn(make_float2(acc[i].z, acc[i].w));
    uint2 pk = make_uint2(*reinterpret_cast<uint*>(&lo), *reinterpret_cast<uint*>(&hi));
    *(uint2*)&out[((size_t)b * 1024 + m) * 256 + n0 + ct * 4] = pk;
  }
}

// ---------------- transpose [B,C,P] -> [B,P,C] bf16, 64x64 tile, 16B stores ----------------
__global__ __launch_bounds__(256) void transpose64_bf16(const float* __restrict__ src, bf16* __restrict__ dst,
                                                        int C, int P) {
  __shared__ float tile[64][65];
  int b = blockIdx.z;
  int p0 = blockIdx.x * 64;
  int c0 = blockIdx.y * 64;
  int t = threadIdx.x;
  int l16 = t & 15, r16 = t >> 4;
#pragma unroll
  for (int pass = 0; pass < 4; ++pass) {
    int c = r16 + pass * 16;
    float4 v = *(const float4*)&src[((size_t)b * C + c0 + c) * P + p0 + l16 * 4];
    tile[c][l16 * 4 + 0] = v.x;
    tile[c][l16 * 4 + 1] = v.y;
    tile[c][l16 * 4 + 2] = v.z;
    tile[c][l16 * 4 + 3] = v.w;
  }
  __syncthreads();
  int l8 = t & 7, r32 = t >> 3;
#pragma unroll
  for (int pass = 0; pass < 2; ++pass) {
    int p = r32 + pass * 32;
    uint r[4];
#pragma unroll
    for (int q = 0; q < 4; ++q) {
      __hip_bfloat162 h2 = __float22bfloat162_rn(make_float2(tile[l8 * 8 + 2 * q][p], tile[l8 * 8 + 2 * q + 1][p]));
      r[q] = *reinterpret_cast<uint*>(&h2);
    }
    *(uint4*)&dst[((size_t)b * P + p0 + p) * C + c0 + l8 * 8] = make_uint4(r[0], r[1], r[2], r[3]);
  }
}

// ---------------- per-scale gather pooling, XCD frame affinity ----------------
__device__ __forceinline__ void accum8(float wt, uint4 u, float* a) {
  a[0] += wt * blo(u.x); a[1] += wt * bhi(u.x);
  a[2] += wt * blo(u.y); a[3] += wt * bhi(u.y);
  a[4] += wt * blo(u.z); a[5] += wt * bhi(u.z);
  a[6] += wt * blo(u.w); a[7] += wt * bhi(u.w);
}

template <int HS, int LPP>
__global__ __launch_bounds__(256) void gather_scale(const bf16* __restrict__ F,
                                                    const int* __restrict__ poff,
                                                    const int* __restrict__ psorted,
                                                    const float* __restrict__ rc,
                                                    float* __restrict__ pout) {
  constexpr int S = 256 / LPP;      // pixel streams
  constexpr int CHUNK = LPP * 8;    // channels this dispatch-slice
  int blk = blockIdx.x;
  int n = ((blk & 7) << 10) | (blk >> 3);   // frame f -> XCD f (round-robin heuristic)
  int b = n >> 10;
  int c0 = blockIdx.y * CHUNK;
  int t = threadIdx.x;
  int l = t & (LPP - 1);
  int s = t / LPP;
  const bf16* fb = F + (size_t)b * (HS * HS) * 256 + c0 + l * 8;
  const float fh = (float)(HS - 1) / 255.0f;
  int j1 = poff[n + 1];
  float acc[8];
#pragma unroll
  for (int i = 0; i < 8; ++i) acc[i] = 0.f;
  for (int j = poff[n] + s; j < j1; j += S) {
    int p = psorted[j];
    int h = (p >> 8) & 255, w = p & 255;
    float ph = h * fh, pw = w * fh;
    int i0 = (int)ph, j0 = (int)pw;
    float th = ph - (float)i0, tw = pw - (float)j0;
    int i1 = min(i0 + 1, HS - 1), jj1 = min(j0 + 1, HS - 1);
    float w11 = th * tw, w10 = th - w11, w01 = tw - w11, w00 = 1.f - th - tw + w11;
    uint4 u00 = *(const uint4*)(fb + (i0 * HS + j0) * 256);
    uint4 u01 = *(const uint4*)(fb + (i0 * HS + jj1) * 256);
    uint4 u10 = *(const uint4*)(fb + (i1 * HS + j0) * 256);
    uint4 u11 = *(const uint4*)(fb + (i1 * HS + jj1) * 256);
    accum8(w00, u00, acc);
    accum8(w01, u01, acc);
    accum8(w10, u10, acc);
    accum8(w11, u11, acc);
  }
  __shared__ float4 red4[512];
  red4[t * 2 + 0] = make_float4(acc[0], acc[1], acc[2], acc[3]);
  red4[t * 2 + 1] = make_float4(acc[4], acc[5], acc[6], acc[7]);
  __syncthreads();
  if (t < LPP * 2) {
    float r = rc[n];
    int l2 = t >> 1, half = t & 1;
    float4 sum = make_float4(0.f, 0.f, 0.f, 0.f);
#pragma unroll
    for (int ss = 0; ss < S; ++ss) {
      float4 v = red4[(ss * LPP + l2) * 2 + half];
      sum.x += v.x; sum.y += v.y; sum.z += v.z; sum.w += v.w;
    }
    sum.x *= r; sum.y *= r; sum.z *= r; sum.w *= r;
    *(float4*)&pout[(size_t)n * 256 + c0 + t * 4] = sum;
  }
}

// ---------------- GEMM with fused mix: out = (0.5*(X+P)) @ W, K=N=256 ----------------
__global__ __launch_bounds__(256) void gemm_mix_n256(const float* __restrict__ X, const float* __restrict__ Pl,
                                                     const float* __restrict__ W, float* __restrict__ out) {
  const int t = threadIdx.x;
  const int r0 = blockIdx.x * 16;
  const int cw = (t & 63) * 4;
  const int rg = (t >> 6) * 4;
  __shared__ float Xl[16][68];
  float4 acc[4];
#pragma unroll
  for (int i = 0; i < 4; ++i) acc[i] = make_float4(0.f, 0.f, 0.f, 0.f);
  for (int k0 = 0; k0 < 256; k0 += 64) {
#pragma unroll
    for (int l = 0; l < 4; ++l) {
      int idx = t + 256 * l;
      int r = idx >> 6, k = idx & 63;
      size_t a = (size_t)(r0 + r) * 256 + k0 + k;
      Xl[r][k] = 0.5f * (X[a] + Pl[a]);
    }
    __syncthreads();
#pragma unroll
    for (int k4 = 0; k4 < 64; k4 += 4) {
      float4 a[4];
#pragma unroll
      for (int i = 0; i < 4; ++i) a[i] = *(const float4*)&Xl[rg + i][k4];
#pragma unroll
      for (int kk = 0; kk < 4; ++kk) {
        float4 w = *(const float4*)&W[(size_t)(k0 + k4 + kk) * 256 + cw];
#pragma unroll
        for (int i = 0; i < 4; ++i) {
          float av = ((const float*)&a[i])[kk];
          acc[i].x += av * w.x;
          acc[i].y += av * w.y;
          acc[i].z += av * w.z;
          acc[i].w += av * w.w;
        }
      }
    }
    __syncthreads();
  }
#pragma unroll
  for (int i = 0; i < 4; ++i)
    *(float4*)&out[(size_t)(r0 + rg + i) * 256 + cw] = acc[i];
}

// ---------------- CSR edge aggregation + bias + relu (linear srcs/ews) ----------------
__global__ __launch_bounds__(256) void agg_kernel(const float* __restrict__ h, const float* __restrict__ bias,
                                                  const int* __restrict__ eoff,
                                                  const int* __restrict__ srcs, const float* __restrict__ ews,
                                                  float* __restrict__ xout) {
  int n = blockIdx.x;
  int c = threadIdx.x;
  int e0 = eoff[n], e1 = eoff[n + 1];
  float acc = 0.f;
  for (int j = e0; j < e1; ++j) {
    acc += ews[j] * h[((size_t)srcs[j] << 8) + c];
  }
  float v = acc + bias[c];
  xout[((size_t)n << 8) + c] = v > 0.f ? v : 0.f;
}

// ---------------- score s = x @ lin_w ----------------
__global__ __launch_bounds__(256) void score_kernel(const float* __restrict__ x, const float* __restrict__ lw,
                                                    float* __restrict__ s) {
  int t = threadIdx.x;
  int n = blockIdx.x * 4 + (t >> 6);
  int lane = t & 63;
  const float* row = x + ((size_t)n << 8);
  float v = row[lane] * lw[lane] + row[lane + 64] * lw[lane + 64] +
            row[lane + 128] * lw[lane + 128] + row[lane + 192] * lw[lane + 192];
#pragma unroll
  for (int off = 32; off > 0; off >>= 1) v += __shfl_down(v, off, 64);
  if (lane == 0) s[n] = v;
}

// ---------------- final sigmoids ----------------
__global__ __launch_bounds__(256) void out_kernel(const float* __restrict__ s, const int* __restrict__ src,
                                                  const int* __restrict__ dst, const int* __restrict__ negs,
                                                  float* __restrict__ outp) {
  int e = blockIdx.x * 256 + threadIdx.x;
  if (e >= EE) return;
  float ss = s[src[e]];
  float a = ss - s[negs[e]];
  float b = ss - s[dst[e]];
  outp[e] = 1.0f / (1.0f + expf(-a));         // dan
  outp[EE + e] = 1.0f / (1.0f + expf(-b));    // dap
}

extern "C" void kernel_launch(void* const* d_in, const int* in_sizes, int n_in,
                              void* d_out, int out_size, void* d_ws, size_t ws_size,
                              hipStream_t stream) {
  const int*   labels = (const int*)d_in[0];
  const float* skip0  = (const float*)d_in[1];
  const float* skip1  = (const float*)d_in[2];
  const float* skip2  = (const float*)d_in[3];
  const int*   edges  = (const int*)d_in[4];
  const int*   negs   = (const int*)d_in[5];
  const float* W0     = (const float*)d_in[6];
  const float* b0     = (const float*)d_in[7];
  const float* W1     = (const float*)d_in[8];
  const float* b1     = (const float*)d_in[9];
  const float* W2     = (const float*)d_in[10];
  const float* b2     = (const float*)d_in[11];
  const float* lw     = (const float*)d_in[12];
  const int* esrc = edges;
  const int* edst = edges + EE;
  float* outp = (float*)d_out;

  // ---- workspace bump allocator (256B aligned) ----
  size_t o = 0;
  char* base = (char*)d_ws;
  auto alloc = [&](size_t bytes) -> void* {
    void* p = base + o;
    o += (bytes + 255) & ~(size_t)255;
    return p;
  };
  // zeroed block (contiguous at front)
  u64* packed  = (u64*)alloc(NNODE * 8);
  int* cnt_e   = (int*)alloc(NNODE * 4);
  int* ecur    = (int*)alloc(NNODE * 4);
  int* pcur    = (int*)alloc(NNODE * 4);
  size_t zbytes = o;
  // non-zeroed
  int*   cntp    = (int*)alloc(NNODE * 4);
  float* rcnt    = (float*)alloc(NNODE * 4);
  float* pch     = (float*)alloc(NNODE * 4);
  float* pcw     = (float*)alloc(NNODE * 4);
  int*   poff    = (int*)alloc((NNODE + 1) * 4);
  int*   eoff    = (int*)alloc((NNODE + 1) * 4);
  int*   srcs    = (int*)alloc(EE * 4);
  float* ews     = (float*)alloc(EE * 4);
  int*   psorted = (int*)alloc(NPIX * 4);
  float* ewb     = (float*)alloc(EE * 4);
  int*   segb    = (int*)alloc(NPIX * 4);
  float* bufA    = (float*)alloc((size_t)NNODE * CH * 4);
  float* bufB    = (float*)alloc((size_t)NNODE * CH * 4);
  float* bufC    = (float*)alloc((size_t)NNODE * CH * 4);
  float* p1buf   = (float*)alloc((size_t)NNODE * CH * 4);
  float* p2buf   = (float*)alloc((size_t)NNODE * CH * 4);
  bf16*  F0b     = (bf16*)alloc((size_t)BB * 1024 * CH * 2);   // 4 MB
  bf16*  F1t     = (bf16*)alloc((size_t)BB * 4096 * CH * 2);   // 16.8 MB
  bf16*  F2t     = (bf16*)alloc((size_t)BB * 16384 * CH * 2);  // 67 MB
  float* sbuf    = (float*)alloc(NNODE * 4);
  (void)ws_size; (void)n_in; (void)in_sizes; (void)out_size;

  // 1. zero accumulators
  zero_kernel<<<64, 256, 0, stream>>>((int4*)d_ws, (int)(zbytes / 16));
  // 2. seg ids + packed count/coord atomics
  seg_cnt_kernel<<<NPIX / 256, 256, 0, stream>>>(labels, segb, packed);
  // 3. decode counts + centroids
  rcnt_kernel<<<NNODE / 256, 256, 0, stream>>>(packed, cntp, rcnt, pch, pcw);
  // 4-5. pixel CSR by seg
  scan_kernel<<<1, 1024, 0, stream>>>(cntp, poff);
  pixel_scatter_kernel<<<NPIX / 256, 256, 0, stream>>>(segb, poff, pcur, psorted);
  // 6-9. edge weights + CSR by dst with fused (src,ew) permute
  edge_cnt_kernel<<<EE / 256, 256, 0, stream>>>(edst, cnt_e);
  scan_kernel<<<1, 1024, 0, stream>>>(cnt_e, eoff);
  edge_attr_kernel<<<EE / 256, 256, 0, stream>>>(esrc, edst, pch, pcw, ewb, outp);
  edge_scatter_kernel<<<EE / 256, 256, 0, stream>>>(edst, esrc, ewb, eoff, ecur, srcs, ews);
  // 10. skip0 @ W0 -> F0b (bf16, channels-last), direct from channel-first
  gemm_kmaj_bf16<<<dim3(32, 2, BB), 256, 0, stream>>>(skip0, W0, F0b);
  // 11-12. skip1/skip2 -> channels-last bf16
  transpose64_bf16<<<dim3(4096 / 64, 4, BB), 256, 0, stream>>>(skip1, F1t, 256, 4096);
  transpose64_bf16<<<dim3(16384 / 64, 4, BB), 256, 0, stream>>>(skip2, F2t, 256, 16384);
  // 13-15. per-scale gather pooling (normalized outputs), XCD frame affinity
  gather_scale<32, 32><<<dim3(NNODE, 1), 256, 0, stream>>>(F0b, poff, psorted, rcnt, bufA);
  gather_scale<64, 32><<<dim3(NNODE, 1), 256, 0, stream>>>(F1t, poff, psorted, rcnt, p1buf);
  gather_scale<128, 16><<<dim3(NNODE, 2), 256, 0, stream>>>(F2t, poff, psorted, rcnt, p2buf);
  // 16. layer0 aggregate -> x1
  agg_kernel<<<NNODE, 256, 0, stream>>>(bufA, b0, eoff, srcs, ews, bufB);
  // 17-18. layer1 (mix fused into GEMM)
  gemm_mix_n256<<<NNODE / 16, 256, 0, stream>>>(bufB, p1buf, W1, bufC);
  agg_kernel<<<NNODE, 256, 0, stream>>>(bufC, b1, eoff, srcs, ews, bufA);
  // 19-20. layer2
  gemm_mix_n256<<<NNODE / 16, 256, 0, stream>>>(bufA, p2buf, W2, bufC);
  agg_kernel<<<NNODE, 256, 0, stream>>>(bufC, b2, eoff, srcs, ews, bufB);
  // 21. s = x3 @ lin_w
  score_kernel<<<NNODE / 4, 256, 0, stream>>>(bufB, lw, sbuf);
  // 22. dan / dap
  out_kernel<<<EE / 256, 256, 0, stream>>>(sbuf, esrc, edst, negs, outp);
}

// Round 5
// 737.954 us; speedup vs baseline: 2.7228x; 1.0498x over previous
//
#include <hip/hip_runtime.h>
#include <hip/hip_bf16.h>
#include <cstdint>
#include <cstddef>

#define BB 8
#define NSPX 1024
#define NNODE 8192      // BB*NSPX
#define EE 131072
#define NPIX 524288     // BB*256*256
#define CH 256

using bf16 = __hip_bfloat16;
typedef unsigned int uint;
typedef unsigned long long u64;

__device__ __forceinline__ float blo(uint u) { return __uint_as_float(u << 16); }
__device__ __forceinline__ float bhi(uint u) { return __uint_as_float(u & 0xffff0000u); }
__device__ __forceinline__ uint packbf2(float a, float b) {
  __hip_bfloat162 h = __float22bfloat162_rn(make_float2(a, b));
  return *reinterpret_cast<uint*>(&h);
}

// ---------------- zero workspace accumulators ----------------
__global__ __launch_bounds__(256) void zero_kernel(int4* p, int n4) {
  int i = blockIdx.x * 256 + threadIdx.x;
  int stride = gridDim.x * 256;
  int4 z = make_int4(0, 0, 0, 0);
  for (; i < n4; i += stride) p[i] = z;
}

// ---------------- fused: seg ids + packed(cnt,h,w) atomics | edge dst counting ----------------
__global__ __launch_bounds__(256) void cnt2_kernel(const int* __restrict__ labels,
                                                   const int* __restrict__ edst,
                                                   int* __restrict__ segb,
                                                   u64* __restrict__ packed,
                                                   int* __restrict__ cnt_e) {
  int blk = blockIdx.x;
  int t = threadIdx.x;
  if (blk < 2048) {
    int p = blk * 256 + t;
    int b = p >> 16;
    int h = (p >> 8) & 255;
    int w = p & 255;
    int seg = labels[p] + (b << 10);
    segb[p] = seg;
    u64 enc = (1ULL << 48) | ((u64)h << 24) | (u64)w;
    atomicAdd(&packed[seg], enc);
  } else {
    int e = (blk - 2048) * 256 + t;
    atomicAdd(&cnt_e[edst[e]], 1);
  }
}

// ---------------- fused dual 8192-length exclusive scan (2 blocks) ----------------
__global__ __launch_bounds__(1024) void scan2_kernel(const u64* __restrict__ packed,
                                                     const int* __restrict__ cnt_e,
                                                     int* __restrict__ poff, int* __restrict__ eoff) {
  __shared__ int ps[1024];
  int which = blockIdx.x;          // 0: pixel counts (from packed), 1: edge counts
  int* coff = which ? eoff : poff;
  int t = threadIdx.x;
  int base = t * 8;
  int v[8];
  int sum = 0;
#pragma unroll
  for (int i = 0; i < 8; ++i) {
    int x = which ? cnt_e[base + i] : (int)(packed[base + i] >> 48);
    v[i] = sum;
    sum += x;
  }
  ps[t] = sum;
  __syncthreads();
  for (int off = 1; off < 1024; off <<= 1) {
    int x = (t >= off) ? ps[t - off] : 0;
    __syncthreads();
    ps[t] += x;
    __syncthreads();
  }
  int prev = (t == 0) ? 0 : ps[t - 1];
#pragma unroll
  for (int i = 0; i < 8; ++i) coff[base + i] = prev + v[i];
  if (t == 1023) coff[8192] = ps[1023];
}

// ---------------- decode 1/cnt + centroids ----------------
__global__ __launch_bounds__(256) void rcnt_kernel(const u64* __restrict__ packed,
                                                   float* __restrict__ rcnt,
                                                   float* __restrict__ pch, float* __restrict__ pcw) {
  int n = blockIdx.x * 256 + threadIdx.x;
  if (n >= NNODE) return;
  u64 v = packed[n];
  int c = (int)(v >> 48);
  int sh = (int)((v >> 24) & 0xFFFFFF);
  int sw = (int)(v & 0xFFFFFF);
  float r = 1.0f / (float)(c > 1 ? c : 1);
  rcnt[n] = r;
  pch[n] = (float)sh * r * (1.0f / 255.0f);
  pcw[n] = (float)sw * r * (1.0f / 255.0f);
}

// ---------------- fused: pixel CSR scatter | edge attr + CSR scatter of (src,ew) ----------------
__global__ __launch_bounds__(256) void scatter2_kernel(const int* __restrict__ segb,
                                                       const int* __restrict__ poff,
                                                       int* __restrict__ pcur,
                                                       int* __restrict__ psorted,
                                                       const int* __restrict__ esrc,
                                                       const int* __restrict__ edst,
                                                       const float* __restrict__ pch,
                                                       const float* __restrict__ pcw,
                                                       const int* __restrict__ eoff,
                                                       int* __restrict__ ecur,
                                                       uint2* __restrict__ evw,
                                                       float* __restrict__ outp) {
  int blk = blockIdx.x;
  int t = threadIdx.x;
  if (blk < 2048) {
    int p = blk * 256 + t;
    int s = segb[p];
    int pos = poff[s] + atomicAdd(&pcur[s], 1);
    psorted[pos] = p;
  } else {
    int e = (blk - 2048) * 256 + t;
    int s1 = esrc[e], d1 = edst[e];
    float dh = pch[s1] - pch[d1];
    float dw = pcw[s1] - pcw[d1];
    float ea = expf(-(dh * dh + dw * dw) * 20.0f);
    outp[2 * EE + e] = ea;
    int pos = eoff[d1] + atomicAdd(&ecur[d1], 1);
    evw[pos] = make_uint2((uint)s1, __float_as_uint(ea));
  }
}

// ---------------- skip0 fold: out[b][m][n] = sum_k skip0[b][k][m] * W0[k][n], bf16 out ----
__global__ __launch_bounds__(256) void gemm_kmaj_bf16(const float* __restrict__ A,
                                                      const float* __restrict__ W,
                                                      bf16* __restrict__ out) {
  __shared__ float As[64][36];   // 64 k x 32 m, stride 36 (16B-aligned, bank-spread)
  int b = blockIdx.z;
  int m0 = blockIdx.x * 32;
  int n0 = blockIdx.y * 128;
  int t = threadIdx.x;
  int ct = t & 31;               // n-quad
  int rm = t >> 5;               // m-group
  int l8 = t & 7, kr = t >> 3;
  const float* Ab = A + (size_t)b * 512 * 1024;
  float4 acc[4];
#pragma unroll
  for (int i = 0; i < 4; ++i) acc[i] = make_float4(0.f, 0.f, 0.f, 0.f);
  for (int k0 = 0; k0 < 512; k0 += 64) {
#pragma unroll
    for (int pass = 0; pass < 2; ++pass) {
      int k = kr + pass * 32;
      float4 v = *(const float4*)&Ab[(size_t)(k0 + k) * 1024 + m0 + l8 * 4];
      *(float4*)&As[k][l8 * 4] = v;
    }
    __syncthreads();
#pragma unroll 8
    for (int k = 0; k < 64; ++k) {
      float4 a = *(const float4*)&As[k][rm * 4];
      float4 wv = *(const float4*)&W[(size_t)(k0 + k) * 256 + n0 + ct * 4];
      acc[0].x += a.x * wv.x; acc[0].y += a.x * wv.y; acc[0].z += a.x * wv.z; acc[0].w += a.x * wv.w;
      acc[1].x += a.y * wv.x; acc[1].y += a.y * wv.y; acc[1].z += a.y * wv.z; acc[1].w += a.y * wv.w;
      acc[2].x += a.z * wv.x; acc[2].y += a.z * wv.y; acc[2].z += a.z * wv.z; acc[2].w += a.z * wv.w;
      acc[3].x += a.w * wv.x; acc[3].y += a.w * wv.y; acc[3].z += a.w * wv.z; acc[3].w += a.w * wv.w;
    }
    __syncthreads();
  }
#pragma unroll
  for (int i = 0; i < 4; ++i) {
    int m = m0 + rm * 4 + i;
    uint2 pk = make_uint2(packbf2(acc[i].x, acc[i].y), packbf2(acc[i].z, acc[i].w));
    *(uint2*)&out[((size_t)b * 1024 + m) * 256 + n0 + ct * 4] = pk;
  }
}

// ---------------- transpose [B,C,P] -> [B,P,C] bf16, 64x64 tile, 16B stores ----------------
__global__ __launch_bounds__(256) void transpose64_bf16(const float* __restrict__ src, bf16* __restrict__ dst,
                                                        int C, int P) {
  __shared__ float tile[64][65];
  int b = blockIdx.z;
  int p0 = blockIdx.x * 64;
  int c0 = blockIdx.y * 64;
  int t = threadIdx.x;
  int l16 = t & 15, r16 = t >> 4;
#pragma unroll
  for (int pass = 0; pass < 4; ++pass) {
    int c = r16 + pass * 16;
    float4 v = *(const float4*)&src[((size_t)b * C + c0 + c) * P + p0 + l16 * 4];
    tile[c][l16 * 4 + 0] = v.x;
    tile[c][l16 * 4 + 1] = v.y;
    tile[c][l16 * 4 + 2] = v.z;
    tile[c][l16 * 4 + 3] = v.w;
  }
  __syncthreads();
  int l8 = t & 7, r32 = t >> 3;
#pragma unroll
  for (int pass = 0; pass < 2; ++pass) {
    int p = r32 + pass * 32;
    uint r[4];
#pragma unroll
    for (int q = 0; q < 4; ++q)
      r[q] = packbf2(tile[l8 * 8 + 2 * q][p], tile[l8 * 8 + 2 * q + 1][p]);
    *(uint4*)&dst[((size_t)b * P + p0 + p) * C + c0 + l8 * 8] = make_uint4(r[0], r[1], r[2], r[3]);
  }
}

// ---------------- gather pooling helpers ----------------
__device__ __forceinline__ void accum8(float wt, uint4 u, float* a) {
  a[0] += wt * blo(u.x); a[1] += wt * bhi(u.x);
  a[2] += wt * blo(u.y); a[3] += wt * bhi(u.y);
  a[4] += wt * blo(u.z); a[5] += wt * bhi(u.z);
  a[6] += wt * blo(u.w); a[7] += wt * bhi(u.w);
}

template <int HS>
__device__ __forceinline__ void taps_scale(const bf16* __restrict__ fb, int h, int w, float* acc) {
  const float fh = (float)(HS - 1) / 255.0f;
  float ph = h * fh, pw = w * fh;
  int i0 = (int)ph, j0 = (int)pw;
  float th = ph - (float)i0, tw = pw - (float)j0;
  int i1 = min(i0 + 1, HS - 1), jj1 = min(j0 + 1, HS - 1);
  float w11 = th * tw, w10 = th - w11, w01 = tw - w11, w00 = 1.f - th - tw + w11;
  uint4 u00 = *(const uint4*)(fb + (i0 * HS + j0) * 256);
  uint4 u01 = *(const uint4*)(fb + (i0 * HS + jj1) * 256);
  uint4 u10 = *(const uint4*)(fb + (i1 * HS + j0) * 256);
  uint4 u11 = *(const uint4*)(fb + (i1 * HS + jj1) * 256);
  accum8(w00, u00, acc);
  accum8(w01, u01, acc);
  accum8(w10, u10, acc);
  accum8(w11, u11, acc);
}

// ---------------- fused gather pooling scales 0+1 (L2-resident), XCD frame affinity ----
// scale0 output bf16 (h0 for layer-0 agg), scale1 output fp32
__global__ __launch_bounds__(256) void gather01_kernel(const bf16* __restrict__ F0,
                                                       const bf16* __restrict__ F1,
                                                       const int* __restrict__ poff,
                                                       const int* __restrict__ psorted,
                                                       const float* __restrict__ rc,
                                                       bf16* __restrict__ p0out,
                                                       float* __restrict__ p1out) {
  int blk = blockIdx.x;
  int n = ((blk & 7) << 10) | (blk >> 3);
  int b = n >> 10;
  int t = threadIdx.x;
  int l = t & 31;        // channel octet
  int s = t >> 5;        // 8 pixel streams
  const bf16* f0 = F0 + (size_t)b * 1024 * 256 + l * 8;
  const bf16* f1 = F1 + (size_t)b * 4096 * 256 + l * 8;
  int j1 = poff[n + 1];
  float a0[8], a1[8];
#pragma unroll
  for (int i = 0; i < 8; ++i) { a0[i] = 0.f; a1[i] = 0.f; }
  for (int j = poff[n] + s; j < j1; j += 8) {
    int p = psorted[j];
    int h = (p >> 8) & 255, w = p & 255;
    taps_scale<32>(f0, h, w, a0);
    taps_scale<64>(f1, h, w, a1);
  }
  __shared__ float4 red[2][512];
  red[0][t * 2 + 0] = make_float4(a0[0], a0[1], a0[2], a0[3]);
  red[0][t * 2 + 1] = make_float4(a0[4], a0[5], a0[6], a0[7]);
  red[1][t * 2 + 0] = make_float4(a1[0], a1[1], a1[2], a1[3]);
  red[1][t * 2 + 1] = make_float4(a1[4], a1[5], a1[6], a1[7]);
  __syncthreads();
  if (t < 64) {
    float r = rc[n];
    int l2 = t >> 1, half = t & 1;
    float4 s0 = make_float4(0.f, 0.f, 0.f, 0.f), s1 = s0;
#pragma unroll
    for (int ss = 0; ss < 8; ++ss) {
      float4 v0 = red[0][(ss * 32 + l2) * 2 + half];
      float4 v1 = red[1][(ss * 32 + l2) * 2 + half];
      s0.x += v0.x; s0.y += v0.y; s0.z += v0.z; s0.w += v0.w;
      s1.x += v1.x; s1.y += v1.y; s1.z += v1.z; s1.w += v1.w;
    }
    s0.x *= r; s0.y *= r; s0.z *= r; s0.w *= r;
    s1.x *= r; s1.y *= r; s1.z *= r; s1.w *= r;
    *(uint2*)&p0out[(size_t)n * 256 + 4 * t] = make_uint2(packbf2(s0.x, s0.y), packbf2(s0.z, s0.w));
    *(float4*)&p1out[(size_t)n * 256 + 4 * t] = s1;
  }
}

// ---------------- gather pooling scale2, 2 channel-halves, XCD frame affinity ----------------
__global__ __launch_bounds__(256) void gather2_kernel(const bf16* __restrict__ F,
                                                      const int* __restrict__ poff,
                                                      const int* __restrict__ psorted,
                                                      const float* __restrict__ rc,
                                                      float* __restrict__ pout) {
  int blk = blockIdx.x;
  int n = ((blk & 7) << 10) | (blk >> 3);
  int b = n >> 10;
  int c0 = blockIdx.y * 128;
  int t = threadIdx.x;
  int l = t & 15;       // channel octet within 128
  int s = t >> 4;       // 16 pixel streams
  const bf16* fb = F + (size_t)b * 16384 * 256 + c0 + l * 8;
  int j1 = poff[n + 1];
  float acc[8];
#pragma unroll
  for (int i = 0; i < 8; ++i) acc[i] = 0.f;
  for (int j = poff[n] + s; j < j1; j += 16) {
    int p = psorted[j];
    int h = (p >> 8) & 255, w = p & 255;
    taps_scale<128>(fb, h, w, acc);
  }
  __shared__ float4 red4[512];
  red4[t * 2 + 0] = make_float4(acc[0], acc[1], acc[2], acc[3]);
  red4[t * 2 + 1] = make_float4(acc[4], acc[5], acc[6], acc[7]);
  __syncthreads();
  if (t < 32) {
    float r = rc[n];
    int l2 = t >> 1, half = t & 1;
    float4 sum = make_float4(0.f, 0.f, 0.f, 0.f);
#pragma unroll
    for (int ss = 0; ss < 16; ++ss) {
      float4 v = red4[(ss * 16 + l2) * 2 + half];
      sum.x += v.x; sum.y += v.y; sum.z += v.z; sum.w += v.w;
    }
    sum.x *= r; sum.y *= r; sum.z *= r; sum.w *= r;
    *(float4*)&pout[(size_t)n * 256 + c0 + t * 4] = sum;
  }
}

// ---------------- GEMM with fused mix: out = (0.5*(X+P)) @ W, K=N=256, bf16 out ----------------
__global__ __launch_bounds__(256) void gemm_mix_n256(const float* __restrict__ X, const float* __restrict__ Pl,
                                                     const float* __restrict__ W, bf16* __restrict__ out) {
  const int t = threadIdx.x;
  const int r0 = blockIdx.x * 16;
  const int cw = (t & 63) * 4;
  const int rg = (t >> 6) * 4;
  __shared__ float Xl[16][68];
  float4 acc[4];
#pragma unroll
  for (int i = 0; i < 4; ++i) acc[i] = make_float4(0.f, 0.f, 0.f, 0.f);
  for (int k0 = 0; k0 < 256; k0 += 64) {
#pragma unroll
    for (int l = 0; l < 4; ++l) {
      int idx = t + 256 * l;
      int r = idx >> 6, k = idx & 63;
      size_t a = (size_t)(r0 + r) * 256 + k0 + k;
      Xl[r][k] = 0.5f * (X[a] + Pl[a]);
    }
    __syncthreads();
#pragma unroll
    for (int k4 = 0; k4 < 64; k4 += 4) {
      float4 a[4];
#pragma unroll
      for (int i = 0; i < 4; ++i) a[i] = *(const float4*)&Xl[rg + i][k4];
#pragma unroll
      for (int kk = 0; kk < 4; ++kk) {
        float4 w = *(const float4*)&W[(size_t)(k0 + k4 + kk) * 256 + cw];
#pragma unroll
        for (int i = 0; i < 4; ++i) {
          float av = ((const float*)&a[i])[kk];
          acc[i].x += av * w.x;
          acc[i].y += av * w.y;
          acc[i].z += av * w.z;
          acc[i].w += av * w.w;
        }
      }
    }
    __syncthreads();
  }
#pragma unroll
  for (int i = 0; i < 4; ++i) {
    uint2 pk = make_uint2(packbf2(acc[i].x, acc[i].y), packbf2(acc[i].z, acc[i].w));
    *(uint2*)&out[(size_t)(r0 + rg + i) * 256 + cw] = pk;
  }
}

// ---------------- CSR edge aggregation + bias + relu; h is bf16, 2 nodes/block ----------------
__global__ __launch_bounds__(256) void agg_kernel(const bf16* __restrict__ h, const float* __restrict__ bias,
                                                  const int* __restrict__ eoff,
                                                  const uint2* __restrict__ evw,
                                                  float* __restrict__ xout) {
  int n = blockIdx.x * 2 + (threadIdx.x >> 7);
  int c2 = threadIdx.x & 127;   // channel pair
  int e0 = eoff[n], e1 = eoff[n + 1];
  float a0 = 0.f, a1 = 0.f;
  for (int j = e0; j < e1; ++j) {
    uint2 ev = evw[j];
    float wv = __uint_as_float(ev.y);
    uint hv = *(const uint*)&h[((size_t)ev.x << 8) + c2 * 2];
    a0 += wv * blo(hv);
    a1 += wv * bhi(hv);
  }
  float v0 = a0 + bias[2 * c2];
  float v1 = a1 + bias[2 * c2 + 1];
  float2 st = make_float2(v0 > 0.f ? v0 : 0.f, v1 > 0.f ? v1 : 0.f);
  *(float2*)&xout[((size_t)n << 8) + 2 * c2] = st;
}

// ---------------- score s = x @ lin_w ----------------
__global__ __launch_bounds__(256) void score_kernel(const float* __restrict__ x, const float* __restrict__ lw,
                                                    float* __restrict__ s) {
  int t = threadIdx.x;
  int n = blockIdx.x * 4 + (t >> 6);
  int lane = t & 63;
  const float* row = x + ((size_t)n << 8);
  float v = row[lane] * lw[lane] + row[lane + 64] * lw[lane + 64] +
            row[lane + 128] * lw[lane + 128] + row[lane + 192] * lw[lane + 192];
#pragma unroll
  for (int off = 32; off > 0; off >>= 1) v += __shfl_down(v, off, 64);
  if (lane == 0) s[n] = v;
}

// ---------------- final sigmoids ----------------
__global__ __launch_bounds__(256) void out_kernel(const float* __restrict__ s, const int* __restrict__ src,
                                                  const int* __restrict__ dst, const int* __restrict__ negs,
                                                  float* __restrict__ outp) {
  int e = blockIdx.x * 256 + threadIdx.x;
  if (e >= EE) return;
  float ss = s[src[e]];
  float a = ss - s[negs[e]];
  float b = ss - s[dst[e]];
  outp[e] = 1.0f / (1.0f + expf(-a));         // dan
  outp[EE + e] = 1.0f / (1.0f + expf(-b));    // dap
}

extern "C" void kernel_launch(void* const* d_in, const int* in_sizes, int n_in,
                              void* d_out, int out_size, void* d_ws, size_t ws_size,
                              hipStream_t stream) {
  const int*   labels = (const int*)d_in[0];
  const float* skip0  = (const float*)d_in[1];
  const float* skip1  = (const float*)d_in[2];
  const float* skip2  = (const float*)d_in[3];
  const int*   edges  = (const int*)d_in[4];
  const int*   negs   = (const int*)d_in[5];
  const float* W0     = (const float*)d_in[6];
  const float* b0     = (const float*)d_in[7];
  const float* W1     = (const float*)d_in[8];
  const float* b1     = (const float*)d_in[9];
  const float* W2     = (const float*)d_in[10];
  const float* b2     = (const float*)d_in[11];
  const float* lw     = (const float*)d_in[12];
  const int* esrc = edges;
  const int* edst = edges + EE;
  float* outp = (float*)d_out;

  // ---- workspace bump allocator (256B aligned) ----
  size_t o = 0;
  char* base = (char*)d_ws;
  auto alloc = [&](size_t bytes) -> void* {
    void* p = base + o;
    o += (bytes + 255) & ~(size_t)255;
    return p;
  };
  // zeroed block (contiguous at front)
  u64* packed  = (u64*)alloc(NNODE * 8);
  int* cnt_e   = (int*)alloc(NNODE * 4);
  int* ecur    = (int*)alloc(NNODE * 4);
  int* pcur    = (int*)alloc(NNODE * 4);
  size_t zbytes = o;
  // non-zeroed
  float* rcnt    = (float*)alloc(NNODE * 4);
  float* pch     = (float*)alloc(NNODE * 4);
  float* pcw     = (float*)alloc(NNODE * 4);
  int*   poff    = (int*)alloc((NNODE + 1) * 4);
  int*   eoff    = (int*)alloc((NNODE + 1) * 4);
  uint2* evw     = (uint2*)alloc((size_t)EE * 8);
  int*   psorted = (int*)alloc(NPIX * 4);
  int*   segb    = (int*)alloc(NPIX * 4);
  float* bufA    = (float*)alloc((size_t)NNODE * CH * 4);
  float* bufB    = (float*)alloc((size_t)NNODE * CH * 4);
  float* p1buf   = (float*)alloc((size_t)NNODE * CH * 4);
  float* p2buf   = (float*)alloc((size_t)NNODE * CH * 4);
  bf16*  h0b     = (bf16*)alloc((size_t)NNODE * CH * 2);       // 4 MB
  bf16*  h1b     = (bf16*)alloc((size_t)NNODE * CH * 2);       // 4 MB (reused for h2)
  bf16*  F0b     = (bf16*)alloc((size_t)BB * 1024 * CH * 2);   // 4 MB
  bf16*  F1t     = (bf16*)alloc((size_t)BB * 4096 * CH * 2);   // 16.8 MB
  bf16*  F2t     = (bf16*)alloc((size_t)BB * 16384 * CH * 2);  // 67 MB
  float* sbuf    = (float*)alloc(NNODE * 4);
  (void)ws_size; (void)n_in; (void)in_sizes; (void)out_size;

  // 1. zero accumulators
  zero_kernel<<<64, 256, 0, stream>>>((int4*)d_ws, (int)(zbytes / 16));
  // 2. fused seg-count + edge-count
  cnt2_kernel<<<2048 + 512, 256, 0, stream>>>(labels, edst, segb, packed, cnt_e);
  // 3. dual scan (pixel counts from packed, edge counts)
  scan2_kernel<<<2, 1024, 0, stream>>>(packed, cnt_e, poff, eoff);
  // 4. 1/cnt + centroids
  rcnt_kernel<<<NNODE / 256, 256, 0, stream>>>(packed, rcnt, pch, pcw);
  // 5. fused pixel CSR scatter + edge attr/CSR scatter (writes edge_attr output)
  scatter2_kernel<<<2048 + 512, 256, 0, stream>>>(segb, poff, pcur, psorted,
                                                  esrc, edst, pch, pcw, eoff, ecur, evw, outp);
  // 6. skip0 @ W0 -> F0b (bf16, channels-last), direct from channel-first
  gemm_kmaj_bf16<<<dim3(32, 2, BB), 256, 0, stream>>>(skip0, W0, F0b);
  // 7-8. skip1/skip2 -> channels-last bf16
  transpose64_bf16<<<dim3(4096 / 64, 4, BB), 256, 0, stream>>>(skip1, F1t, 256, 4096);
  transpose64_bf16<<<dim3(16384 / 64, 4, BB), 256, 0, stream>>>(skip2, F2t, 256, 16384);
  // 9-10. gather pooling: scales 0+1 fused; scale2 in 2 channel-halves
  gather01_kernel<<<NNODE, 256, 0, stream>>>(F0b, F1t, poff, psorted, rcnt, h0b, p1buf);
  gather2_kernel<<<dim3(NNODE, 2), 256, 0, stream>>>(F2t, poff, psorted, rcnt, p2buf);
  // 11. layer0 aggregate (h0 bf16) -> x1
  agg_kernel<<<NNODE / 2, 256, 0, stream>>>(h0b, b0, eoff, evw, bufB);
  // 12-13. layer1 (mix fused into GEMM, bf16 h out)
  gemm_mix_n256<<<NNODE / 16, 256, 0, stream>>>(bufB, p1buf, W1, h1b);
  agg_kernel<<<NNODE / 2, 256, 0, stream>>>(h1b, b1, eoff, evw, bufA);
  // 14-15. layer2
  gemm_mix_n256<<<NNODE / 16, 256, 0, stream>>>(bufA, p2buf, W2, h1b);
  agg_kernel<<<NNODE / 2, 256, 0, stream>>>(h1b, b2, eoff, evw, bufB);
  // 16. s = x3 @ lin_w
  score_kernel<<<NNODE / 4, 256, 0, stream>>>(bufB, lw, sbuf);
  // 17. dan / dap
  out_kernel<<<EE / 256, 256, 0, stream>>>(sbuf, esrc, edst, negs, outp);
}

// Round 6
// 728.325 us; speedup vs baseline: 2.7588x; 1.0132x over previous
//
#include <hip/hip_runtime.h>
#include <hip/hip_fp16.h>
#include <cstdint>
#include <cstddef>

#define BB 8
#define NSPX 1024
#define NNODE 8192      // BB*NSPX
#define EE 131072
#define NPIX 524288     // BB*256*256
#define CH 256

typedef unsigned int uint;
typedef unsigned long long u64;

__device__ __forceinline__ uint packh2(float a, float b) {
  __half2 h = __float22half2_rn(make_float2(a, b));
  return *reinterpret_cast<uint*>(&h);
}
__device__ __forceinline__ __half2 uh2(uint u) { return *reinterpret_cast<__half2*>(&u); }
__device__ __forceinline__ uint h2u(__half2 h) { return *reinterpret_cast<uint*>(&h); }

// ---------------- zero workspace accumulators ----------------
__global__ __launch_bounds__(256) void zero_kernel(int4* p, int n4) {
  int i = blockIdx.x * 256 + threadIdx.x;
  int stride = gridDim.x * 256;
  int4 z = make_int4(0, 0, 0, 0);
  for (; i < n4; i += stride) p[i] = z;
}

// ---------------- fused: seg ids + packed(cnt,h,w) atomics | edge dst counting ----------------
__global__ __launch_bounds__(256) void cnt2_kernel(const int* __restrict__ labels,
                                                   const int* __restrict__ edst,
                                                   int* __restrict__ segb,
                                                   u64* __restrict__ packed,
                                                   int* __restrict__ cnt_e) {
  int blk = blockIdx.x;
  int t = threadIdx.x;
  if (blk < 2048) {
    int p = blk * 256 + t;
    int b = p >> 16;
    int h = (p >> 8) & 255;
    int w = p & 255;
    int seg = labels[p] + (b << 10);
    segb[p] = seg;
    u64 enc = (1ULL << 48) | ((u64)h << 24) | (u64)w;
    atomicAdd(&packed[seg], enc);
  } else {
    int e = (blk - 2048) * 256 + t;
    atomicAdd(&cnt_e[edst[e]], 1);
  }
}

// ---------------- fused dual 8192-length exclusive scan (2 blocks) ----------------
__global__ __launch_bounds__(1024) void scan2_kernel(const u64* __restrict__ packed,
                                                     const int* __restrict__ cnt_e,
                                                     int* __restrict__ poff, int* __restrict__ eoff) {
  __shared__ int ps[1024];
  int which = blockIdx.x;          // 0: pixel counts (from packed), 1: edge counts
  int* coff = which ? eoff : poff;
  int t = threadIdx.x;
  int base = t * 8;
  int v[8];
  int sum = 0;
#pragma unroll
  for (int i = 0; i < 8; ++i) {
    int x = which ? cnt_e[base + i] : (int)(packed[base + i] >> 48);
    v[i] = sum;
    sum += x;
  }
  ps[t] = sum;
  __syncthreads();
  for (int off = 1; off < 1024; off <<= 1) {
    int x = (t >= off) ? ps[t - off] : 0;
    __syncthreads();
    ps[t] += x;
    __syncthreads();
  }
  int prev = (t == 0) ? 0 : ps[t - 1];
#pragma unroll
  for (int i = 0; i < 8; ++i) coff[base + i] = prev + v[i];
  if (t == 1023) coff[8192] = ps[1023];
}

// ---------------- decode 1/cnt + centroids ----------------
__global__ __launch_bounds__(256) void rcnt_kernel(const u64* __restrict__ packed,
                                                   float* __restrict__ rcnt,
                                                   float* __restrict__ pch, float* __restrict__ pcw) {
  int n = blockIdx.x * 256 + threadIdx.x;
  if (n >= NNODE) return;
  u64 v = packed[n];
  int c = (int)(v >> 48);
  int sh = (int)((v >> 24) & 0xFFFFFF);
  int sw = (int)(v & 0xFFFFFF);
  float r = 1.0f / (float)(c > 1 ? c : 1);
  rcnt[n] = r;
  pch[n] = (float)sh * r * (1.0f / 255.0f);
  pcw[n] = (float)sw * r * (1.0f / 255.0f);
}

// ---------------- fused: pixel CSR scatter | edge attr + CSR scatter of (src,ew) ----------------
__global__ __launch_bounds__(256) void scatter2_kernel(const int* __restrict__ segb,
                                                       const int* __restrict__ poff,
                                                       int* __restrict__ pcur,
                                                       int* __restrict__ psorted,
                                                       const int* __restrict__ esrc,
                                                       const int* __restrict__ edst,
                                                       const float* __restrict__ pch,
                                                       const float* __restrict__ pcw,
                                                       const int* __restrict__ eoff,
                                                       int* __restrict__ ecur,
                                                       uint2* __restrict__ evw,
                                                       float* __restrict__ outp) {
  int blk = blockIdx.x;
  int t = threadIdx.x;
  if (blk < 2048) {
    int p = blk * 256 + t;
    int s = segb[p];
    int pos = poff[s] + atomicAdd(&pcur[s], 1);
    psorted[pos] = p;
  } else {
    int e = (blk - 2048) * 256 + t;
    int s1 = esrc[e], d1 = edst[e];
    float dh = pch[s1] - pch[d1];
    float dw = pcw[s1] - pcw[d1];
    float ea = expf(-(dh * dh + dw * dw) * 20.0f);
    outp[2 * EE + e] = ea;
    int pos = eoff[d1] + atomicAdd(&ecur[d1], 1);
    evw[pos] = make_uint2((uint)s1, __float_as_uint(ea));
  }
}

// ---------------- skip0 fold: out[b][m][n] = sum_k skip0[b][k][m] * W0[k][n], f16 out ----
__global__ __launch_bounds__(256) void gemm_kmaj_f16(const float* __restrict__ A,
                                                     const float* __restrict__ W,
                                                     __half* __restrict__ out) {
  __shared__ float As[64][36];   // 64 k x 32 m, stride 36 (16B-aligned, bank-spread)
  int b = blockIdx.z;
  int m0 = blockIdx.x * 32;
  int n0 = blockIdx.y * 128;
  int t = threadIdx.x;
  int ct = t & 31;               // n-quad
  int rm = t >> 5;               // m-group
  int l8 = t & 7, kr = t >> 3;
  const float* Ab = A + (size_t)b * 512 * 1024;
  float4 acc[4];
#pragma unroll
  for (int i = 0; i < 4; ++i) acc[i] = make_float4(0.f, 0.f, 0.f, 0.f);
  for (int k0 = 0; k0 < 512; k0 += 64) {
#pragma unroll
    for (int pass = 0; pass < 2; ++pass) {
      int k = kr + pass * 32;
      float4 v = *(const float4*)&Ab[(size_t)(k0 + k) * 1024 + m0 + l8 * 4];
      *(float4*)&As[k][l8 * 4] = v;
    }
    __syncthreads();
#pragma unroll 8
    for (int k = 0; k < 64; ++k) {
      float4 a = *(const float4*)&As[k][rm * 4];
      float4 wv = *(const float4*)&W[(size_t)(k0 + k) * 256 + n0 + ct * 4];
      acc[0].x += a.x * wv.x; acc[0].y += a.x * wv.y; acc[0].z += a.x * wv.z; acc[0].w += a.x * wv.w;
      acc[1].x += a.y * wv.x; acc[1].y += a.y * wv.y; acc[1].z += a.y * wv.z; acc[1].w += a.y * wv.w;
      acc[2].x += a.z * wv.x; acc[2].y += a.z * wv.y; acc[2].z += a.z * wv.z; acc[2].w += a.z * wv.w;
      acc[3].x += a.w * wv.x; acc[3].y += a.w * wv.y; acc[3].z += a.w * wv.z; acc[3].w += a.w * wv.w;
    }
    __syncthreads();
  }
#pragma unroll
  for (int i = 0; i < 4; ++i) {
    int m = m0 + rm * 4 + i;
    uint2 pk = make_uint2(packh2(acc[i].x, acc[i].y), packh2(acc[i].z, acc[i].w));
    *(uint2*)&out[((size_t)b * 1024 + m) * 256 + n0 + ct * 4] = pk;
  }
}

// ---------------- transpose [B,C,P] -> [B,P,C] f16, 64x64 tile, 16B stores ----------------
__global__ __launch_bounds__(256) void transpose64_f16(const float* __restrict__ src, __half* __restrict__ dst,
                                                       int C, int P) {
  __shared__ float tile[64][65];
  int b = blockIdx.z;
  int p0 = blockIdx.x * 64;
  int c0 = blockIdx.y * 64;
  int t = threadIdx.x;
  int l16 = t & 15, r16 = t >> 4;
#pragma unroll
  for (int pass = 0; pass < 4; ++pass) {
    int c = r16 + pass * 16;
    float4 v = *(const float4*)&src[((size_t)b * C + c0 + c) * P + p0 + l16 * 4];
    tile[c][l16 * 4 + 0] = v.x;
    tile[c][l16 * 4 + 1] = v.y;
    tile[c][l16 * 4 + 2] = v.z;
    tile[c][l16 * 4 + 3] = v.w;
  }
  __syncthreads();
  int l8 = t & 7, r32 = t >> 3;
#pragma unroll
  for (int pass = 0; pass < 2; ++pass) {
    int p = r32 + pass * 32;
    uint r[4];
#pragma unroll
    for (int q = 0; q < 4; ++q)
      r[q] = packh2(tile[l8 * 8 + 2 * q][p], tile[l8 * 8 + 2 * q + 1][p]);
    *(uint4*)&dst[((size_t)b * P + p0 + p) * C + c0 + l8 * 8] = make_uint4(r[0], r[1], r[2], r[3]);
  }
}

// ---------------- gather pooling: packed-f16 tap accumulate (16 ch / lane) ----------------
__device__ __forceinline__ void tap16(const __half* __restrict__ tp, float wt, __half2* acc) {
  uint4 qa = *(const uint4*)tp;
  uint4 qb = *(const uint4*)(tp + 8);
  __half2 W = __float2half2_rn(wt);
  acc[0] = __hfma2(W, uh2(qa.x), acc[0]);
  acc[1] = __hfma2(W, uh2(qa.y), acc[1]);
  acc[2] = __hfma2(W, uh2(qa.z), acc[2]);
  acc[3] = __hfma2(W, uh2(qa.w), acc[3]);
  acc[4] = __hfma2(W, uh2(qb.x), acc[4]);
  acc[5] = __hfma2(W, uh2(qb.y), acc[5]);
  acc[6] = __hfma2(W, uh2(qb.z), acc[6]);
  acc[7] = __hfma2(W, uh2(qb.w), acc[7]);
}

template <int HS>
__device__ __forceinline__ void taps16(const __half* __restrict__ fb, int h, int w, __half2* acc) {
  const float fh = (float)(HS - 1) / 255.0f;
  float ph = h * fh, pw = w * fh;
  int i0 = (int)ph, j0 = (int)pw;
  float th = ph - (float)i0, tw = pw - (float)j0;
  int i1 = min(i0 + 1, HS - 1), jj1 = min(j0 + 1, HS - 1);
  float w11 = th * tw, w10 = th - w11, w01 = tw - w11, w00 = 1.f - th - tw + w11;
  tap16(fb + (i0 * HS + j0) * 256, w00, acc);
  tap16(fb + (i0 * HS + jj1) * 256, w01, acc);
  tap16(fb + (i1 * HS + j0) * 256, w10, acc);
  tap16(fb + (i1 * HS + jj1) * 256, w11, acc);
}

// ---------------- fused gather scales 0+1 (L2-resident), XCD frame affinity ----------------
// 16 lanes x 16ch, 16 pixel streams. scale0 out f16 (h0), scale1 out fp32.
__global__ __launch_bounds__(256) void gather01_kernel(const __half* __restrict__ F0,
                                                       const __half* __restrict__ F1,
                                                       const int* __restrict__ poff,
                                                       const int* __restrict__ psorted,
                                                       const float* __restrict__ rc,
                                                       __half* __restrict__ p0out,
                                                       float* __restrict__ p1out) {
  int blk = blockIdx.x;
  int n = ((blk & 7) << 10) | (blk >> 3);   // frame f -> XCD f
  int b = n >> 10;
  int t = threadIdx.x;
  int l = t & 15;       // channel 16-group
  int s = t >> 4;       // 16 pixel streams
  const __half* f0 = F0 + (size_t)b * 1024 * 256 + l * 16;
  const __half* f1 = F1 + (size_t)b * 4096 * 256 + l * 16;
  int j1 = poff[n + 1];
  __half2 z = __float2half2_rn(0.f);
  __half2 a0[8], a1[8];
#pragma unroll
  for (int i = 0; i < 8; ++i) { a0[i] = z; a1[i] = z; }
  for (int j = poff[n] + s; j < j1; j += 16) {
    int p = psorted[j];
    int h = (p >> 8) & 255, w = p & 255;
    taps16<32>(f0, h, w, a0);
    taps16<64>(f1, h, w, a1);
  }
  __shared__ uint red[2][256][9];   // 18 KB, stride-9 pad
#pragma unroll
  for (int k = 0; k < 8; ++k) { red[0][t][k] = h2u(a0[k]); red[1][t][k] = h2u(a1[k]); }
  __syncthreads();
  if (t < 128) {
    int l2 = t >> 3, k = t & 7;
    float r = rc[n];
    float2 s0 = make_float2(0.f, 0.f), s1 = s0;
#pragma unroll
    for (int ss = 0; ss < 16; ++ss) {
      float2 v0 = __half22float2(uh2(red[0][ss * 16 + l2][k]));
      float2 v1 = __half22float2(uh2(red[1][ss * 16 + l2][k]));
      s0.x += v0.x; s0.y += v0.y;
      s1.x += v1.x; s1.y += v1.y;
    }
    int c = l2 * 16 + k * 2;
    *(uint*)&p0out[(size_t)n * 256 + c] = packh2(s0.x * r, s0.y * r);
    *(float2*)&p1out[(size_t)n * 256 + c] = make_float2(s1.x * r, s1.y * r);
  }
}

// ---------------- gather scale2, 2 channel-halves (L2-resident), XCD frame affinity ----------------
// 8 lanes x 16ch, 32 pixel streams.
__global__ __launch_bounds__(256) void gather2_kernel(const __half* __restrict__ F,
                                                      const int* __restrict__ poff,
                                                      const int* __restrict__ psorted,
                                                      const float* __restrict__ rc,
                                                      float* __restrict__ pout) {
  int blk = blockIdx.x;
  int n = ((blk & 7) << 10) | (blk >> 3);
  int b = n >> 10;
  int c0 = blockIdx.y * 128;
  int t = threadIdx.x;
  int l = t & 7;        // channel 16-group within 128
  int s = t >> 3;       // 32 pixel streams
  const __half* fb = F + (size_t)b * 16384 * 256 + c0 + l * 16;
  int j1 = poff[n + 1];
  __half2 z = __float2half2_rn(0.f);
  __half2 acc[8];
#pragma unroll
  for (int i = 0; i < 8; ++i) acc[i] = z;
  for (int j = poff[n] + s; j < j1; j += 32) {
    int p = psorted[j];
    int h = (p >> 8) & 255, w = p & 255;
    taps16<128>(fb, h, w, acc);
  }
  __shared__ uint red[256][9];   // 9 KB
#pragma unroll
  for (int k = 0; k < 8; ++k) red[t][k] = h2u(acc[k]);
  __syncthreads();
  if (t < 64) {
    int l2 = t >> 3, k = t & 7;
    float r = rc[n];
    float2 sm = make_float2(0.f, 0.f);
#pragma unroll
    for (int ss = 0; ss < 32; ++ss) {
      float2 v = __half22float2(uh2(red[ss * 8 + l2][k]));
      sm.x += v.x; sm.y += v.y;
    }
    int c = c0 + l2 * 16 + k * 2;
    *(float2*)&pout[(size_t)n * 256 + c] = make_float2(sm.x * r, sm.y * r);
  }
}

// ---------------- GEMM with fused mix: out = (0.5*(X+P)) @ W, K=N=256, f16 out ----------------
__global__ __launch_bounds__(256) void gemm_mix_n256(const float* __restrict__ X, const float* __restrict__ Pl,
                                                     const float* __restrict__ W, __half* __restrict__ out) {
  const int t = threadIdx.x;
  const int r0 = blockIdx.x * 16;
  const int cw = (t & 63) * 4;
  const int rg = (t >> 6) * 4;
  __shared__ float Xl[16][68];
  float4 acc[4];
#pragma unroll
  for (int i = 0; i < 4; ++i) acc[i] = make_float4(0.f, 0.f, 0.f, 0.f);
  for (int k0 = 0; k0 < 256; k0 += 64) {
#pragma unroll
    for (int l = 0; l < 4; ++l) {
      int idx = t + 256 * l;
      int r = idx >> 6, k = idx & 63;
      size_t a = (size_t)(r0 + r) * 256 + k0 + k;
      Xl[r][k] = 0.5f * (X[a] + Pl[a]);
    }
    __syncthreads();
#pragma unroll
    for (int k4 = 0; k4 < 64; k4 += 4) {
      float4 a[4];
#pragma unroll
      for (int i = 0; i < 4; ++i) a[i] = *(const float4*)&Xl[rg + i][k4];
#pragma unroll
      for (int kk = 0; kk < 4; ++kk) {
        float4 w = *(const float4*)&W[(size_t)(k0 + k4 + kk) * 256 + cw];
#pragma unroll
        for (int i = 0; i < 4; ++i) {
          float av = ((const float*)&a[i])[kk];
          acc[i].x += av * w.x;
          acc[i].y += av * w.y;
          acc[i].z += av * w.z;
          acc[i].w += av * w.w;
        }
      }
    }
    __syncthreads();
  }
#pragma unroll
  for (int i = 0; i < 4; ++i) {
    uint2 pk = make_uint2(packh2(acc[i].x, acc[i].y), packh2(acc[i].z, acc[i].w));
    *(uint2*)&out[(size_t)(r0 + rg + i) * 256 + cw] = pk;
  }
}

// ---------------- CSR edge aggregation + bias + relu; h is f16, 2 nodes/block ----------------
__global__ __launch_bounds__(256) void agg_kernel(const __half* __restrict__ h, const float* __restrict__ bias,
                                                  const int* __restrict__ eoff,
                                                  const uint2* __restrict__ evw,
                                                  float* __restrict__ xout) {
  int n = blockIdx.x * 2 + (threadIdx.x >> 7);
  int c2 = threadIdx.x & 127;   // channel pair
  int e0 = eoff[n], e1 = eoff[n + 1];
  float a0 = 0.f, a1 = 0.f;
  for (int j = e0; j < e1; ++j) {
    uint2 ev = evw[j];
    float wv = __uint_as_float(ev.y);
    uint hv = *(const uint*)&h[((size_t)ev.x << 8) + c2 * 2];
    float2 f = __half22float2(uh2(hv));
    a0 += wv * f.x;
    a1 += wv * f.y;
  }
  float v0 = a0 + bias[2 * c2];
  float v1 = a1 + bias[2 * c2 + 1];
  float2 st = make_float2(v0 > 0.f ? v0 : 0.f, v1 > 0.f ? v1 : 0.f);
  *(float2*)&xout[((size_t)n << 8) + 2 * c2] = st;
}

// ---------------- score s = x @ lin_w ----------------
__global__ __launch_bounds__(256) void score_kernel(const float* __restrict__ x, const float* __restrict__ lw,
                                                    float* __restrict__ s) {
  int t = threadIdx.x;
  int n = blockIdx.x * 4 + (t >> 6);
  int lane = t & 63;
  const float* row = x + ((size_t)n << 8);
  float v = row[lane] * lw[lane] + row[lane + 64] * lw[lane + 64] +
            row[lane + 128] * lw[lane + 128] + row[lane + 192] * lw[lane + 192];
#pragma unroll
  for (int off = 32; off > 0; off >>= 1) v += __shfl_down(v, off, 64);
  if (lane == 0) s[n] = v;
}

// ---------------- final sigmoids ----------------
__global__ __launch_bounds__(256) void out_kernel(const float* __restrict__ s, const int* __restrict__ src,
                                                  const int* __restrict__ dst, const int* __restrict__ negs,
                                                  float* __restrict__ outp) {
  int e = blockIdx.x * 256 + threadIdx.x;
  if (e >= EE) return;
  float ss = s[src[e]];
  float a = ss - s[negs[e]];
  float b = ss - s[dst[e]];
  outp[e] = 1.0f / (1.0f + expf(-a));         // dan
  outp[EE + e] = 1.0f / (1.0f + expf(-b));    // dap
}

extern "C" void kernel_launch(void* const* d_in, const int* in_sizes, int n_in,
                              void* d_out, int out_size, void* d_ws, size_t ws_size,
                              hipStream_t stream) {
  const int*   labels = (const int*)d_in[0];
  const float* skip0  = (const float*)d_in[1];
  const float* skip1  = (const float*)d_in[2];
  const float* skip2  = (const float*)d_in[3];
  const int*   edges  = (const int*)d_in[4];
  const int*   negs   = (const int*)d_in[5];
  const float* W0     = (const float*)d_in[6];
  const float* b0     = (const float*)d_in[7];
  const float* W1     = (const float*)d_in[8];
  const float* b1     = (const float*)d_in[9];
  const float* W2     = (const float*)d_in[10];
  const float* b2     = (const float*)d_in[11];
  const float* lw     = (const float*)d_in[12];
  const int* esrc = edges;
  const int* edst = edges + EE;
  float* outp = (float*)d_out;

  // ---- workspace bump allocator (256B aligned) ----
  size_t o = 0;
  char* base = (char*)d_ws;
  auto alloc = [&](size_t bytes) -> void* {
    void* p = base + o;
    o += (bytes + 255) & ~(size_t)255;
    return p;
  };
  // zeroed block (contiguous at front)
  u64* packed  = (u64*)alloc(NNODE * 8);
  int* cnt_e   = (int*)alloc(NNODE * 4);
  int* ecur    = (int*)alloc(NNODE * 4);
  int* pcur    = (int*)alloc(NNODE * 4);
  size_t zbytes = o;
  // non-zeroed
  float*  rcnt    = (float*)alloc(NNODE * 4);
  float*  pch     = (float*)alloc(NNODE * 4);
  float*  pcw     = (float*)alloc(NNODE * 4);
  int*    poff    = (int*)alloc((NNODE + 1) * 4);
  int*    eoff    = (int*)alloc((NNODE + 1) * 4);
  uint2*  evw     = (uint2*)alloc((size_t)EE * 8);
  int*    psorted = (int*)alloc(NPIX * 4);
  int*    segb    = (int*)alloc(NPIX * 4);
  float*  bufA    = (float*)alloc((size_t)NNODE * CH * 4);
  float*  bufB    = (float*)alloc((size_t)NNODE * CH * 4);
  float*  p1buf   = (float*)alloc((size_t)NNODE * CH * 4);
  float*  p2buf   = (float*)alloc((size_t)NNODE * CH * 4);
  __half* h0b     = (__half*)alloc((size_t)NNODE * CH * 2);       // 4 MB
  __half* h1b     = (__half*)alloc((size_t)NNODE * CH * 2);       // 4 MB (reused for h2)
  __half* F0b     = (__half*)alloc((size_t)BB * 1024 * CH * 2);   // 4 MB
  __half* F1t     = (__half*)alloc((size_t)BB * 4096 * CH * 2);   // 16.8 MB
  __half* F2t     = (__half*)alloc((size_t)BB * 16384 * CH * 2);  // 67 MB
  float*  sbuf    = (float*)alloc(NNODE * 4);
  (void)ws_size; (void)n_in; (void)in_sizes; (void)out_size;

  // 1. zero accumulators
  zero_kernel<<<64, 256, 0, stream>>>((int4*)d_ws, (int)(zbytes / 16));
  // 2. fused seg-count + edge-count
  cnt2_kernel<<<2048 + 512, 256, 0, stream>>>(labels, edst, segb, packed, cnt_e);
  // 3. dual scan (pixel counts from packed, edge counts)
  scan2_kernel<<<2, 1024, 0, stream>>>(packed, cnt_e, poff, eoff);
  // 4. 1/cnt + centroids
  rcnt_kernel<<<NNODE / 256, 256, 0, stream>>>(packed, rcnt, pch, pcw);
  // 5. fused pixel CSR scatter + edge attr/CSR scatter (writes edge_attr output)
  scatter2_kernel<<<2048 + 512, 256, 0, stream>>>(segb, poff, pcur, psorted,
                                                  esrc, edst, pch, pcw, eoff, ecur, evw, outp);
  // 6. skip0 @ W0 -> F0b (f16, channels-last), direct from channel-first
  gemm_kmaj_f16<<<dim3(32, 2, BB), 256, 0, stream>>>(skip0, W0, F0b);
  // 7-8. skip1/skip2 -> channels-last f16
  transpose64_f16<<<dim3(4096 / 64, 4, BB), 256, 0, stream>>>(skip1, F1t, 256, 4096);
  transpose64_f16<<<dim3(16384 / 64, 4, BB), 256, 0, stream>>>(skip2, F2t, 256, 16384);
  // 9-10. gather pooling: scales 0+1 fused; scale2 in 2 channel-halves
  gather01_kernel<<<NNODE, 256, 0, stream>>>(F0b, F1t, poff, psorted, rcnt, h0b, p1buf);
  gather2_kernel<<<dim3(NNODE, 2), 256, 0, stream>>>(F2t, poff, psorted, rcnt, p2buf);
  // 11. layer0 aggregate (h0 f16) -> x1
  agg_kernel<<<NNODE / 2, 256, 0, stream>>>(h0b, b0, eoff, evw, bufB);
  // 12-13. layer1 (mix fused into GEMM, f16 h out)
  gemm_mix_n256<<<NNODE / 16, 256, 0, stream>>>(bufB, p1buf, W1, h1b);
  agg_kernel<<<NNODE / 2, 256, 0, stream>>>(h1b, b1, eoff, evw, bufA);
  // 14-15. layer2
  gemm_mix_n256<<<NNODE / 16, 256, 0, stream>>>(bufA, p2buf, W2, h1b);
  agg_kernel<<<NNODE / 2, 256, 0, stream>>>(h1b, b2, eoff, evw, bufB);
  // 16. s = x3 @ lin_w
  score_kernel<<<NNODE / 4, 256, 0, stream>>>(bufB, lw, sbuf);
  // 17. dan / dap
  out_kernel<<<EE / 256, 256, 0, stream>>>(sbuf, esrc, edst, negs, outp);
}